// Round 4
// baseline (288.149 us; speedup 1.0000x reference)
//
#include <hip/hip_runtime.h>

#define CCH 128      // channels
#define WIN 128      // time window (exact: receptive field of last step = 122)
#define TLEN 2048
#define NBATCH 8
#define NATOMS 3584
#define NEG 0.2f
#define NBLK 128     // 8 batches x 16 col-groups; all co-resident on 256 CUs

struct Params {
    const float *x, *embed_w, *posamp_w, *posamp_b, *reduce_w, *reduce_b;
    const float *dil_w, *dil_b, *one_w, *one_b;
    const float *aw1, *ab1, *aw2, *ab2, *aw3, *ab3;
    const float *pw1, *pb1, *pw2, *pb2, *pw3, *pb3;
    float *buf0, *buf1;
    int   *bar;          // [0]=cnt, [1]=gen  (memset to 0 each call)
    float *out;
};

__device__ __forceinline__ float lrelu(float v) { return v >= 0.f ? v : NEG * v; }

// Device-wide barrier: all NBLK blocks guaranteed co-resident
// (128 blocks x 8 waves = 1024 waves << 256 CU x 8-wave capacity at VGPR<=256).
__device__ __forceinline__ void dbar(int* cnt, int* gen) {
    __threadfence();                     // release my block's writes (device scope)
    __syncthreads();
    if (threadIdx.x == 0) {
        int g = __hip_atomic_load(gen, __ATOMIC_RELAXED, __HIP_MEMORY_SCOPE_AGENT);
        int a = __hip_atomic_fetch_add(cnt, 1, __ATOMIC_RELAXED, __HIP_MEMORY_SCOPE_AGENT);
        if (a == NBLK - 1) {
            __hip_atomic_store(cnt, 0, __ATOMIC_RELAXED, __HIP_MEMORY_SCOPE_AGENT);
            __threadfence();             // cnt reset + all data before gen bump
            __hip_atomic_store(gen, g + 1, __ATOMIC_RELAXED, __HIP_MEMORY_SCOPE_AGENT);
        } else {
            while (__hip_atomic_load(gen, __ATOMIC_RELAXED, __HIP_MEMORY_SCOPE_AGENT) == g)
                __builtin_amdgcn_s_sleep(1);
        }
        __threadfence();                 // acquire remote writes (invalidates L1)
    }
    __syncthreads();
}

// Thread (c = tid&127, sl = tid>>7). Block: batch b = bid>>4, cols [wg*8, wg*8+8).
// K-split over sl: each thread holds 1/4 of the weight row (one copy per block),
// computes partials for all 8 columns; reduce via LDS. Activation LDS reads are
// wave-uniform (sl wave-uniform) -> free broadcasts, no bank conflicts.
__global__ void __launch_bounds__(512, 2) fused(Params P)
{
    const int bid = blockIdx.x;
    const int b   = bid >> 4;
    const int wg  = bid & 15;
    const int w0  = wg * 8;
    const int tid = threadIdx.x;
    const int c   = tid & (CCH - 1);
    const int sl  = tid >> 7;            // 0..3, wave-uniform

    __shared__ float cols[3][8][CCH];    // 12 KB: taps -d,0,+d
    __shared__ float ybuf[8][CCH];       //  4 KB
    __shared__ float part[8][4][CCH];    // 16 KB: K-split partials
    __shared__ float cat[8][2 * CCH];    //  8 KB: setup concat
    __shared__ float hf[CCH], h1a[CCH], h2a[CCH], h1p[CCH], h2p[CCH];

    // ---------------- setup: h0 = reduce([embed | posamp]) ----------------
    {
        const float* xb = P.x + b * 4 * TLEN;
        for (int q = 0; q < 2; ++q) {
            int p = sl + q * 4;
            int t = TLEN - WIN + w0 + p;
            int idx = (int)xb[t];                    // atom id (exact int in f32)
            float pos = xb[TLEN + t];
            float amp = xb[2 * TLEN + t];
            cat[p][c]       = P.embed_w[idx * CCH + c];
            cat[p][CCH + c] = P.posamp_w[2 * c] * pos + P.posamp_w[2 * c + 1] * amp
                            + P.posamp_b[c];
        }
        __syncthreads();
        const float4* rw = (const float4*)(P.reduce_w + c * (2 * CCH) + sl * 64);
        float4 W[16];
        #pragma unroll
        for (int j = 0; j < 16; ++j) W[j] = rw[j];
        #pragma unroll
        for (int col = 0; col < 8; ++col) {
            float acc = 0.f;
            #pragma unroll
            for (int g = 0; g < 16; ++g) {
                float4 a4 = *(const float4*)&cat[col][sl * 64 + 4 * g];
                acc += W[g].x * a4.x + W[g].y * a4.y + W[g].z * a4.z + W[g].w * a4.w;
            }
            part[col][sl][c] = acc;
        }
        __syncthreads();
        for (int v = tid; v < 1024; v += 512) {
            int col = v >> 7, ch = v & (CCH - 1);
            float y = part[col][0][ch] + part[col][1][ch] + part[col][2][ch]
                    + part[col][3][ch] + P.reduce_b[ch];
            P.buf0[(b * WIN + w0 + col) * CCH + ch] = y;
        }
    }
    dbar(P.bar, P.bar + 1);

    // ---------------- 6 residual dilated blocks ----------------
    const int dils[6] = {1, 3, 9, 27, 81, 1};
    float* bufs[2] = {P.buf0, P.buf1};
    int cur = 0;
    for (int l = 0; l < 6; ++l) {
        const int d = dils[l];
        const float* hin  = bufs[cur];
        float* hout       = bufs[cur ^ 1];
        const float* Wd = P.dil_w + (size_t)l * CCH * CCH * 3;
        const float* bd = P.dil_b + (size_t)l * CCH;
        const float* Wo = P.one_w + (size_t)l * CCH * CCH;
        const float* bo = P.one_b + (size_t)l * CCH;

        // stage 24 columns (3 taps x 8 cols), zero-fill outside window
        const float* hb = hin + b * WIN * CCH;
        for (int v = tid; v < 768; v += 512) {
            int tap = v >> 8, rem = v & 255, col = rem >> 5, f4 = rem & 31;
            int wp = w0 + col + (tap - 1) * d;
            float4 val = make_float4(0.f, 0.f, 0.f, 0.f);
            if (wp >= 0 && wp < WIN)
                val = *(const float4*)(hb + wp * CCH + f4 * 4);
            *(float4*)&cols[tap][col][f4 * 4] = val;
        }
        __syncthreads();

        // dilated k=3 conv partial over in-channels [sl*32, sl*32+32)
        {
            const float4* Wr = (const float4*)(Wd + c * (CCH * 3) + sl * 96);
            float4 W[24];
            #pragma unroll
            for (int j = 0; j < 24; ++j) W[j] = Wr[j];
            #pragma unroll
            for (int col = 0; col < 8; ++col) {
                float acc = 0.f;
                #pragma unroll
                for (int g = 0; g < 8; ++g) {
                    float4 fm = *(const float4*)&cols[0][col][sl * 32 + 4 * g];
                    float4 fc = *(const float4*)&cols[1][col][sl * 32 + 4 * g];
                    float4 fp = *(const float4*)&cols[2][col][sl * 32 + 4 * g];
                    float4 wA = W[g * 3], wB = W[g * 3 + 1], wC = W[g * 3 + 2];
                    acc += wA.x * fm.x + wA.y * fc.x + wA.z * fp.x + wA.w * fm.y;
                    acc += wB.x * fc.y + wB.y * fp.y + wB.z * fm.z + wB.w * fc.z;
                    acc += wC.x * fp.z + wC.y * fm.w + wC.z * fc.w + wC.w * fp.w;
                }
                part[col][sl][c] = acc;
            }
        }
        __syncthreads();
        for (int v = tid; v < 1024; v += 512) {
            int col = v >> 7, ch = v & (CCH - 1);
            ybuf[col][ch] = part[col][0][ch] + part[col][1][ch] + part[col][2][ch]
                          + part[col][3][ch] + bd[ch];
        }
        __syncthreads();

        // 1x1 conv partial over [sl*32, sl*32+32)
        {
            const float4* Or = (const float4*)(Wo + c * CCH + sl * 32);
            float4 W[8];
            #pragma unroll
            for (int j = 0; j < 8; ++j) W[j] = Or[j];
            #pragma unroll
            for (int col = 0; col < 8; ++col) {
                float acc = 0.f;
                #pragma unroll
                for (int g = 0; g < 8; ++g) {
                    float4 a4 = *(const float4*)&ybuf[col][sl * 32 + 4 * g];
                    acc += W[g].x * a4.x + W[g].y * a4.y + W[g].z * a4.z + W[g].w * a4.w;
                }
                part[col][sl][c] = acc;
            }
        }
        __syncthreads();
        for (int v = tid; v < 1024; v += 512) {
            int col = v >> 7, ch = v & (CCH - 1);
            float z = part[col][0][ch] + part[col][1][ch] + part[col][2][ch]
                    + part[col][3][ch] + bo[ch];
            float h = lrelu(z + cols[1][col][ch]);   // + residual
            hout[(b * WIN + w0 + col) * CCH + ch] = h;
        }
        cur ^= 1;
        dbar(P.bar, P.bar + 1);
    }

    // ---------------- heads (each block redundantly; rows split by wg) ----
    const float* hfin = bufs[cur];
    if (tid < CCH) hf[tid] = hfin[(b * WIN + (WIN - 1)) * CCH + tid];
    __syncthreads();

    if (tid < CCH) {
        const float4* r = (const float4*)(P.aw1 + tid * CCH);
        float s = P.ab1[tid];
        #pragma unroll 8
        for (int k = 0; k < 32; ++k) {
            float4 w4 = r[k];
            s += w4.x * hf[4*k] + w4.y * hf[4*k+1] + w4.z * hf[4*k+2] + w4.w * hf[4*k+3];
        }
        h1a[tid] = lrelu(s);
    } else if (tid < 2 * CCH) {
        int cc = tid - CCH;
        const float4* r = (const float4*)(P.pw1 + cc * CCH);
        float s = P.pb1[cc];
        #pragma unroll 8
        for (int k = 0; k < 32; ++k) {
            float4 w4 = r[k];
            s += w4.x * hf[4*k] + w4.y * hf[4*k+1] + w4.z * hf[4*k+2] + w4.w * hf[4*k+3];
        }
        h1p[cc] = lrelu(s);
    }
    __syncthreads();

    if (tid < CCH) {
        const float4* r = (const float4*)(P.aw2 + tid * CCH);
        float s = P.ab2[tid];
        #pragma unroll 8
        for (int k = 0; k < 32; ++k) {
            float4 w4 = r[k];
            s += w4.x * h1a[4*k] + w4.y * h1a[4*k+1] + w4.z * h1a[4*k+2] + w4.w * h1a[4*k+3];
        }
        h2a[tid] = lrelu(s);
    } else if (tid < 2 * CCH) {
        int cc = tid - CCH;
        const float4* r = (const float4*)(P.pw2 + cc * CCH);
        float s = P.pb2[cc];
        #pragma unroll 8
        for (int k = 0; k < 32; ++k) {
            float4 w4 = r[k];
            s += w4.x * h1p[4*k] + w4.y * h1p[4*k+1] + w4.z * h1p[4*k+2] + w4.w * h1p[4*k+3];
        }
        h2p[cc] = lrelu(s);
    }
    __syncthreads();

    // atom logits: 3584 rows / 16 col-groups = 224 rows per block
    if (tid < 224) {
        int row = wg * 224 + tid;
        const float4* r = (const float4*)(P.aw3 + (size_t)row * CCH);
        float s = P.ab3[row];
        #pragma unroll 8
        for (int k = 0; k < 32; ++k) {
            float4 w4 = r[k];
            s += w4.x * h2a[4*k] + w4.y * h2a[4*k+1] + w4.z * h2a[4*k+2] + w4.w * h2a[4*k+3];
        }
        P.out[b * NATOMS + row] = s;
    } else if (wg == 0 && tid >= 224 && tid < 226) {
        int cc = tid - 224;
        const float* r = P.pw3 + cc * CCH;
        float s = P.pb3[cc];
        for (int k = 0; k < CCH; ++k) s += r[k] * h2p[k];
        P.out[NBATCH * NATOMS + b * 2 + cc] = s;
    }
}

// ---------------------------------------------------------------------------
extern "C" void kernel_launch(void* const* d_in, const int* in_sizes, int n_in,
                              void* d_out, int out_size, void* d_ws, size_t ws_size,
                              hipStream_t stream)
{
    Params P;
    P.x        = (const float*)d_in[0];
    P.embed_w  = (const float*)d_in[1];
    P.posamp_w = (const float*)d_in[2];
    P.posamp_b = (const float*)d_in[3];
    P.reduce_w = (const float*)d_in[4];
    P.reduce_b = (const float*)d_in[5];
    P.dil_w    = (const float*)d_in[6];
    P.dil_b    = (const float*)d_in[7];
    P.one_w    = (const float*)d_in[8];
    P.one_b    = (const float*)d_in[9];
    P.aw1 = (const float*)d_in[10]; P.ab1 = (const float*)d_in[11];
    P.aw2 = (const float*)d_in[12]; P.ab2 = (const float*)d_in[13];
    P.aw3 = (const float*)d_in[14]; P.ab3 = (const float*)d_in[15];
    P.pw1 = (const float*)d_in[16]; P.pb1 = (const float*)d_in[17];
    P.pw2 = (const float*)d_in[18]; P.pb2 = (const float*)d_in[19];
    P.pw3 = (const float*)d_in[20]; P.pb3 = (const float*)d_in[21];

    char* ws = (char*)d_ws;
    P.bar  = (int*)ws;                               // 2 ints, zeroed below
    P.buf0 = (float*)(ws + 256);                     // [8][128][128]
    P.buf1 = P.buf0 + NBATCH * WIN * CCH;            // [8][128][128]
    P.out  = (float*)d_out;

    hipMemsetAsync(d_ws, 0, 256, stream);            // barrier state must be 0
    fused<<<dim3(NBLK), dim3(512), 0, stream>>>(P);
}

// Round 5
// 95.266 us; speedup vs baseline: 3.0247x; 3.0247x over previous
//
#include <hip/hip_runtime.h>

#define CCH 128      // channels
#define TLEN 2048
#define NBATCH 8
#define NATOMS 3584
#define NEG 0.2f

// 7-bit packed index lists (up to 9 slots in 63 bits)
#define PK1(a) ((unsigned long long)(a))
#define PK2(a,b) (PK1(a)|((unsigned long long)(b)<<7))
#define PK3(a,b,c) (PK2(a,b)|((unsigned long long)(c)<<14))
#define PK4(a,b,c,d) (PK3(a,b,c)|((unsigned long long)(d)<<21))
#define PK9(a,b,c,d,e,f,g,h,i) (PK4(a,b,c,d)|((unsigned long long)(e)<<28)| \
    ((unsigned long long)(f)<<35)|((unsigned long long)(g)<<42)| \
    ((unsigned long long)(h)<<49)|((unsigned long long)(i)<<56))

__device__ __forceinline__ float lrelu(float v) { return v >= 0.f ? v : NEG * v; }

// One residual dilated block over nb (<=9) scratch columns.
// Thread (c = tid&127, sl = tid>>7): K-split over sl; LDS activation reads are
// wave-uniform broadcasts. pm/pc/pp/pd: packed src(-d), src(0)=residual,
// src(+d), dst column indices. Mask: dst col forced 0 when a0+jd >= 128
// (right zero-padding beyond t=2047). gout!=null (nb==1): write global.
__device__ __forceinline__ void conv_block(
        const float (*src)[CCH], float (*dst)[CCH], float* gout,
        unsigned long long pm, unsigned long long pc, unsigned long long pp,
        unsigned long long pd, int nb, int a0,
        const float* __restrict__ Wd, const float* __restrict__ bd,
        const float* __restrict__ Wo, const float* __restrict__ bo,
        float (*part)[4][CCH], float (*ybuf)[CCH],
        int c, int sl, int tid)
{
    __syncthreads();   // prior writers of src/part done
    {
        const float4* Wr = (const float4*)(Wd + c * (CCH * 3) + sl * 96);
        float4 W[24];
        #pragma unroll
        for (int j = 0; j < 24; ++j) W[j] = Wr[j];
        for (int s = 0; s < nb; ++s) {
            int jm = (int)((pm >> (7 * s)) & 127);
            int jc = (int)((pc >> (7 * s)) & 127);
            int jp = (int)((pp >> (7 * s)) & 127);
            const float* fm = src[jm] + sl * 32;
            const float* fc = src[jc] + sl * 32;
            const float* fp = src[jp] + sl * 32;
            float acc = 0.f;
            #pragma unroll
            for (int g = 0; g < 8; ++g) {
                float4 m4 = *(const float4*)(fm + 4 * g);
                float4 c4 = *(const float4*)(fc + 4 * g);
                float4 p4 = *(const float4*)(fp + 4 * g);
                float4 wA = W[g * 3], wB = W[g * 3 + 1], wC = W[g * 3 + 2];
                acc += wA.x * m4.x + wA.y * c4.x + wA.z * p4.x + wA.w * m4.y;
                acc += wB.x * c4.y + wB.y * p4.y + wB.z * m4.z + wB.w * c4.z;
                acc += wC.x * p4.z + wC.y * m4.w + wC.z * c4.w + wC.w * p4.w;
            }
            part[s][sl][c] = acc;
        }
    }
    __syncthreads();
    for (int v = tid; v < nb * CCH; v += 512) {
        int s = v >> 7, ch = v & (CCH - 1);
        ybuf[s][ch] = part[s][0][ch] + part[s][1][ch] + part[s][2][ch]
                    + part[s][3][ch] + bd[ch];
    }
    __syncthreads();
    {
        const float4* Or = (const float4*)(Wo + c * CCH + sl * 32);
        float4 V[8];
        #pragma unroll
        for (int j = 0; j < 8; ++j) V[j] = Or[j];
        for (int s = 0; s < nb; ++s) {
            const float* y = ybuf[s] + sl * 32;
            float acc = 0.f;
            #pragma unroll
            for (int g = 0; g < 8; ++g) {
                float4 a4 = *(const float4*)(y + 4 * g);
                acc += V[g].x * a4.x + V[g].y * a4.y + V[g].z * a4.z + V[g].w * a4.w;
            }
            part[s][sl][c] = acc;
        }
    }
    __syncthreads();
    for (int v = tid; v < nb * CCH; v += 512) {
        int s = v >> 7, ch = v & (CCH - 1);
        int jc = (int)((pc >> (7 * s)) & 127);
        int jd = (int)((pd >> (7 * s)) & 127);
        float z = part[s][0][ch] + part[s][1][ch] + part[s][2][ch]
                + part[s][3][ch] + bo[ch];
        float h = lrelu(z + src[jc][ch]);
        if (gout) gout[ch] = h;
        else      dst[jd][ch] = (a0 + jd < 128) ? h : 0.f;
    }
}

// ---------------------------------------------------------------------------
// K1: backward-cone for one L3 column. 80 blocks (b = bid/10, i = bid%10),
// own abs col = 18 + 27*(i>>1) + (i&1)  -> {18,19,45,46,72,73,99,100,126,127}.
// Scratch coords j: abs = a0 + j, a0 = own-13; own at j=13.
// setup j in [0,27); L1 (d=1) dst {1,4,..,25}; L2 (d=3) dst {4,13,22};
// L3 (d=9) dst {13} -> l3c[b][i][:]. All exact (deepest reach abs>=5).
// ---------------------------------------------------------------------------
__global__ void __launch_bounds__(512) k_cone(
        const float* __restrict__ x,
        const float* __restrict__ embed_w,
        const float* __restrict__ posamp_w,
        const float* __restrict__ posamp_b,
        const float* __restrict__ reduce_w,
        const float* __restrict__ reduce_b,
        const float* __restrict__ dil_w,
        const float* __restrict__ dil_b,
        const float* __restrict__ one_w,
        const float* __restrict__ one_b,
        float* __restrict__ l3c)
{
    const int bid = blockIdx.x;
    const int b   = bid / 10;
    const int i   = bid - b * 10;
    const int own = 18 + 27 * (i >> 1) + (i & 1);
    const int a0  = own - 13;
    const int tid = threadIdx.x;
    const int c   = tid & (CCH - 1);
    const int sl  = tid >> 7;

    __shared__ float A[28][CCH];           // 14.3 KB
    __shared__ float B[28][CCH];           // 14.3 KB
    __shared__ float part[9][4][CCH];      // 18.4 KB
    __shared__ float ybuf[9][CCH];         //  4.6 KB
    __shared__ float cat[8][2 * CCH];      //  8.2 KB

    // ---- setup: A[j] = reduce([embed | posamp]) for j in [0,27) ----
    const float* xb = x + b * 4 * TLEN;
    const float4* rw = (const float4*)(reduce_w + c * (2 * CCH) + sl * 64);
    float4 RW[16];
    #pragma unroll
    for (int j = 0; j < 16; ++j) RW[j] = rw[j];

    for (int cb = 0; cb < 4; ++cb) {
        const int cb0 = cb * 8;
        const int nb  = (cb < 3) ? 8 : 3;
        for (int q = 0; q < 2; ++q) {
            int p = sl + q * 4;
            if (p < nb) {
                int j  = cb0 + p;
                int ab = a0 + j;                 // >= 5 always
                float ev = 0.f, pv = 0.f;
                if (ab < 128) {
                    int t = (TLEN - 128) + ab;
                    int idx = (int)xb[t];        // atom id (exact int in f32)
                    float pos = xb[TLEN + t];
                    float amp = xb[2 * TLEN + t];
                    ev = embed_w[idx * CCH + c];
                    pv = posamp_w[2 * c] * pos + posamp_w[2 * c + 1] * amp
                       + posamp_b[c];
                }
                cat[p][c]       = ev;
                cat[p][CCH + c] = pv;
            }
        }
        __syncthreads();
        for (int s = 0; s < nb; ++s) {
            const float* sc = &cat[s][sl * 64];
            float acc = 0.f;
            #pragma unroll
            for (int g = 0; g < 16; ++g) {
                float4 a4 = *(const float4*)(sc + 4 * g);
                acc += RW[g].x * a4.x + RW[g].y * a4.y
                     + RW[g].z * a4.z + RW[g].w * a4.w;
            }
            part[s][sl][c] = acc;
        }
        __syncthreads();
        for (int v = tid; v < nb * CCH; v += 512) {
            int s = v >> 7, ch = v & (CCH - 1);
            int j = cb0 + s;
            float val = part[s][0][ch] + part[s][1][ch] + part[s][2][ch]
                      + part[s][3][ch] + reduce_b[ch];
            A[j][ch] = (a0 + j < 128) ? val : 0.f;
        }
        __syncthreads();
    }

    // ---- L1 (d=1): A -> B, dst {1,4,7,10,13,16,19,22,25} ----
    conv_block(A, B, nullptr,
               PK9(0,3,6,9,12,15,18,21,24),
               PK9(1,4,7,10,13,16,19,22,25),
               PK9(2,5,8,11,14,17,20,23,26),
               PK9(1,4,7,10,13,16,19,22,25), 9, a0,
               dil_w, dil_b, one_w, one_b, part, ybuf, c, sl, tid);
    // ---- L2 (d=3): B -> A, dst {4,13,22} ----
    conv_block(B, A, nullptr,
               PK3(1,10,19), PK3(4,13,22), PK3(7,16,25), PK3(4,13,22), 3, a0,
               dil_w + (size_t)1 * CCH * CCH * 3, dil_b + CCH,
               one_w + (size_t)1 * CCH * CCH, one_b + CCH,
               part, ybuf, c, sl, tid);
    // ---- L3 (d=9): A -> global l3c[b][i] ----
    conv_block(A, A, l3c + (size_t)(b * 10 + i) * CCH,
               PK1(4), PK1(13), PK1(22), PK1(13), 1, a0,
               dil_w + (size_t)2 * CCH * CCH * 3, dil_b + 2 * CCH,
               one_w + (size_t)2 * CCH * CCH, one_b + 2 * CCH,
               part, ybuf, c, sl, tid);
}

// ---------------------------------------------------------------------------
// K2: L4 (d=27) {45,46,126,127} -> L5 (d=81) {126,127} -> L6 (d=1) {127}
// -> MLP heads. 64 blocks (b = bid>>3, g = bid&7); each block recomputes the
// tail, then does atom rows [g*448, g*448+448).
// l3c index map: 0:18 1:19 2:45 3:46 4:72 5:73 6:99 7:100 8:126 9:127.
// ---------------------------------------------------------------------------
__global__ void __launch_bounds__(512) k_tail(
        const float* __restrict__ l3c,
        const float* __restrict__ dil_w,
        const float* __restrict__ dil_b,
        const float* __restrict__ one_w,
        const float* __restrict__ one_b,
        const float* __restrict__ aw1, const float* __restrict__ ab1,
        const float* __restrict__ aw2, const float* __restrict__ ab2,
        const float* __restrict__ aw3, const float* __restrict__ ab3,
        const float* __restrict__ pw1, const float* __restrict__ pb1,
        const float* __restrict__ pw2, const float* __restrict__ pb2,
        const float* __restrict__ pw3, const float* __restrict__ pb3,
        float* __restrict__ out)
{
    const int bid = blockIdx.x;
    const int b   = bid >> 3;
    const int g   = bid & 7;
    const int tid = threadIdx.x;
    const int c   = tid & (CCH - 1);
    const int sl  = tid >> 7;

    __shared__ float A2[11][CCH];          // 10 L3 cols + Z(10)
    __shared__ float B2[5][CCH];           // l4 {45,46,126,127} + Z(4)
    __shared__ float C2[3][CCH];           // l5 {126,127} + Z(2)
    __shared__ float HF[1][CCH];           // l6 {127}
    __shared__ float part[4][4][CCH];
    __shared__ float ybuf[4][CCH];
    __shared__ float h1a[CCH], h2a[CCH], h1p[CCH], h2p[CCH];

    if (tid < CCH) { A2[10][tid] = 0.f; B2[4][tid] = 0.f; C2[2][tid] = 0.f; }
    if (tid < 320) {
        int col = tid >> 5, f4 = tid & 31;
        *(float4*)&A2[col][f4 * 4] =
            *(const float4*)(l3c + (size_t)(b * 10 + col) * CCH + f4 * 4);
    }

    // L4 (d=27): dst {45,46,126,127}; taps: 45:{18,45,72} 46:{19,46,73}
    // 126:{99,126,pad} 127:{100,127,pad}
    conv_block(A2, B2, nullptr,
               PK4(0,1,6,7), PK4(2,3,8,9), PK4(4,5,10,10), PK4(0,1,2,3),
               4, -1000,
               dil_w + (size_t)3 * CCH * CCH * 3, dil_b + 3 * CCH,
               one_w + (size_t)3 * CCH * CCH, one_b + 3 * CCH,
               part, ybuf, c, sl, tid);
    // L5 (d=81): dst {126,127}: 126:{45,126,pad} 127:{46,127,pad}
    conv_block(B2, C2, nullptr,
               PK2(0,1), PK2(2,3), PK2(4,4), PK2(0,1), 2, -1000,
               dil_w + (size_t)4 * CCH * CCH * 3, dil_b + 4 * CCH,
               one_w + (size_t)4 * CCH * CCH, one_b + 4 * CCH,
               part, ybuf, c, sl, tid);
    // L6 (d=1): dst {127}: {126,127,pad}
    conv_block(C2, HF, nullptr,
               PK1(0), PK1(1), PK1(2), PK1(0), 1, -1000,
               dil_w + (size_t)5 * CCH * CCH * 3, dil_b + 5 * CCH,
               one_w + (size_t)5 * CCH * CCH, one_b + 5 * CCH,
               part, ybuf, c, sl, tid);
    __syncthreads();

    // ---- MLP hidden layers (atom stack rows on tid<128, pa on tid<256) ----
    if (tid < CCH) {
        const float4* r = (const float4*)(aw1 + tid * CCH);
        float s = ab1[tid];
        #pragma unroll 8
        for (int k = 0; k < 32; ++k) {
            float4 w4 = r[k];
            s += w4.x * HF[0][4*k] + w4.y * HF[0][4*k+1]
               + w4.z * HF[0][4*k+2] + w4.w * HF[0][4*k+3];
        }
        h1a[tid] = lrelu(s);
    } else if (tid < 2 * CCH) {
        int cc = tid - CCH;
        const float4* r = (const float4*)(pw1 + cc * CCH);
        float s = pb1[cc];
        #pragma unroll 8
        for (int k = 0; k < 32; ++k) {
            float4 w4 = r[k];
            s += w4.x * HF[0][4*k] + w4.y * HF[0][4*k+1]
               + w4.z * HF[0][4*k+2] + w4.w * HF[0][4*k+3];
        }
        h1p[cc] = lrelu(s);
    }
    __syncthreads();
    if (tid < CCH) {
        const float4* r = (const float4*)(aw2 + tid * CCH);
        float s = ab2[tid];
        #pragma unroll 8
        for (int k = 0; k < 32; ++k) {
            float4 w4 = r[k];
            s += w4.x * h1a[4*k] + w4.y * h1a[4*k+1]
               + w4.z * h1a[4*k+2] + w4.w * h1a[4*k+3];
        }
        h2a[tid] = lrelu(s);
    } else if (tid < 2 * CCH) {
        int cc = tid - CCH;
        const float4* r = (const float4*)(pw2 + cc * CCH);
        float s = pb2[cc];
        #pragma unroll 8
        for (int k = 0; k < 32; ++k) {
            float4 w4 = r[k];
            s += w4.x * h1p[4*k] + w4.y * h1p[4*k+1]
               + w4.z * h1p[4*k+2] + w4.w * h1p[4*k+3];
        }
        h2p[cc] = lrelu(s);
    }
    __syncthreads();

    // ---- atom logits: rows [g*448, g*448+448) ----
    if (tid < 448) {
        int row = g * 448 + tid;
        const float4* r = (const float4*)(aw3 + (size_t)row * CCH);
        float s = ab3[row];
        #pragma unroll 8
        for (int k = 0; k < 32; ++k) {
            float4 w4 = r[k];
            s += w4.x * h2a[4*k] + w4.y * h2a[4*k+1]
               + w4.z * h2a[4*k+2] + w4.w * h2a[4*k+3];
        }
        out[b * NATOMS + row] = s;
    } else if (g == 0 && tid < 450) {
        int cc = tid - 448;
        const float* r = pw3 + cc * CCH;
        float s = pb3[cc];
        for (int k = 0; k < CCH; ++k) s += r[k] * h2p[k];
        out[NBATCH * NATOMS + b * 2 + cc] = s;
    }
}

// ---------------------------------------------------------------------------
extern "C" void kernel_launch(void* const* d_in, const int* in_sizes, int n_in,
                              void* d_out, int out_size, void* d_ws, size_t ws_size,
                              hipStream_t stream)
{
    const float* x        = (const float*)d_in[0];
    const float* embed_w  = (const float*)d_in[1];
    const float* posamp_w = (const float*)d_in[2];
    const float* posamp_b = (const float*)d_in[3];
    const float* reduce_w = (const float*)d_in[4];
    const float* reduce_b = (const float*)d_in[5];
    const float* dil_w    = (const float*)d_in[6];
    const float* dil_b    = (const float*)d_in[7];
    const float* one_w    = (const float*)d_in[8];
    const float* one_b    = (const float*)d_in[9];
    const float* aw1 = (const float*)d_in[10]; const float* ab1 = (const float*)d_in[11];
    const float* aw2 = (const float*)d_in[12]; const float* ab2 = (const float*)d_in[13];
    const float* aw3 = (const float*)d_in[14]; const float* ab3 = (const float*)d_in[15];
    const float* pw1 = (const float*)d_in[16]; const float* pb1 = (const float*)d_in[17];
    const float* pw2 = (const float*)d_in[18]; const float* pb2 = (const float*)d_in[19];
    const float* pw3 = (const float*)d_in[20]; const float* pb3 = (const float*)d_in[21];

    float* l3c = (float*)d_ws;     // [8][10][128] f32 = 40 KB

    k_cone<<<dim3(80), dim3(512), 0, stream>>>(
        x, embed_w, posamp_w, posamp_b, reduce_w, reduce_b,
        dil_w, dil_b, one_w, one_b, l3c);

    k_tail<<<dim3(64), dim3(512), 0, stream>>>(
        l3c, dil_w, dil_b, one_w, one_b,
        aw1, ab1, aw2, ab2, aw3, ab3,
        pw1, pb1, pw2, pb2, pw3, pb3, (float*)d_out);
}

// Round 6
// 78.772 us; speedup vs baseline: 3.6580x; 1.2094x over previous
//
#include <hip/hip_runtime.h>

#define CCH 128      // channels
#define TLEN 2048
#define NBATCH 8
#define NATOMS 3584
#define NEG 0.2f

// 7-bit packed index lists (up to 9 slots in 63 bits)
#define PK1(a) ((unsigned long long)(a))
#define PK2(a,b) (PK1(a)|((unsigned long long)(b)<<7))
#define PK3(a,b,c) (PK2(a,b)|((unsigned long long)(c)<<14))
#define PK4(a,b,c,d) (PK3(a,b,c)|((unsigned long long)(d)<<21))
#define PK9(a,b,c,d,e,f,g,h,i) (PK4(a,b,c,d)|((unsigned long long)(e)<<28)| \
    ((unsigned long long)(f)<<35)|((unsigned long long)(g)<<42)| \
    ((unsigned long long)(h)<<49)|((unsigned long long)(i)<<56))

__device__ __forceinline__ float lrelu(float v) { return v >= 0.f ? v : NEG * v; }

// Sum across the 4 K-split partners (adjacent lanes: tid = c*4 + sl).
__device__ __forceinline__ float redsl(float v) {
    v += __shfl_xor(v, 1);
    v += __shfl_xor(v, 2);
    return v;
}

// One residual dilated block over nb (<=9) scratch columns.
// Thread (c = tid>>2, sl = tid&3): K-split over sl, reduced via shfl (same
// wave). Weight registers are loaded pre-rotated by (j+2sl)&7 so LDS
// activation reads are bank-staggered across sl with compile-time reg indices.
// pm/pc/pp/pd: packed src(-d), src(0)=residual, src(+d), dst columns.
// dst col forced 0 when a0+jd >= 128 (right zero-padding beyond t=2047).
// gout!=null (nb==1): write result to gout[c] instead of dst.
__device__ __forceinline__ void conv_block(
        const float (*src)[CCH], float (*dst)[CCH], float* gout,
        unsigned long long pm, unsigned long long pc, unsigned long long pp,
        unsigned long long pd, int nb, int a0,
        const float* __restrict__ Wd, const float* __restrict__ bd,
        const float* __restrict__ Wo, const float* __restrict__ bo,
        float (*ybuf)[CCH], int c, int sl)
{
    const int sl2 = 2 * sl;
    const int slb = sl * 32;                 // float offset of my quarter
    __syncthreads();                         // src ready, ybuf free
    // ---- dilated k=3 conv: partial over in-channels [sl*32, sl*32+32) ----
    {
        const float4* Wr = (const float4*)(Wd + c * (CCH * 3) + sl * 96);
        float4 W[24];
        #pragma unroll
        for (int j = 0; j < 8; ++j) {
            int jr = (j + sl2) & 7;
            W[3*j]   = Wr[3*jr];
            W[3*j+1] = Wr[3*jr+1];
            W[3*j+2] = Wr[3*jr+2];
        }
        for (int s = 0; s < nb; ++s) {
            int jm = (int)((pm >> (7*s)) & 127);
            int jc = (int)((pc >> (7*s)) & 127);
            int jp = (int)((pp >> (7*s)) & 127);
            const float* fm = src[jm] + slb;
            const float* fc = src[jc] + slb;
            const float* fp = src[jp] + slb;
            float aM = 0.f, aC = 0.f, aP = 0.f;   // 3 independent chains
            #pragma unroll
            for (int g = 0; g < 8; ++g) {
                int gr = ((g + sl2) & 7) * 4;
                float4 m4 = *(const float4*)(fm + gr);
                float4 c4 = *(const float4*)(fc + gr);
                float4 p4 = *(const float4*)(fp + gr);
                float4 wA = W[3*g], wB = W[3*g+1], wC = W[3*g+2];
                aM += wA.x*m4.x + wA.w*m4.y + wB.z*m4.z + wC.y*m4.w;
                aC += wA.y*c4.x + wB.x*c4.y + wB.w*c4.z + wC.z*c4.w;
                aP += wA.z*p4.x + wB.y*p4.y + wC.x*p4.z + wC.w*p4.w;
            }
            float tot = redsl(aM + aC + aP);
            if (sl == 0) ybuf[s][c] = tot + bd[c];
        }
    }
    __syncthreads();                         // ybuf ready
    // ---- 1x1 conv + residual + lrelu ----
    {
        const float4* Or = (const float4*)(Wo + c * CCH + slb);
        float4 V[8];
        #pragma unroll
        for (int j = 0; j < 8; ++j) V[j] = Or[(j + sl2) & 7];
        for (int s = 0; s < nb; ++s) {
            int jc = (int)((pc >> (7*s)) & 127);
            int jd = (int)((pd >> (7*s)) & 127);
            const float* y = ybuf[s] + slb;
            float a0v = 0.f, a1v = 0.f;          // 2 independent chains
            #pragma unroll
            for (int g = 0; g < 8; g += 2) {
                int gr0 = ((g     + sl2) & 7) * 4;
                int gr1 = ((g + 1 + sl2) & 7) * 4;
                float4 x0 = *(const float4*)(y + gr0);
                float4 x1 = *(const float4*)(y + gr1);
                float4 v0 = V[g], v1 = V[g+1];
                a0v += v0.x*x0.x + v0.y*x0.y + v0.z*x0.z + v0.w*x0.w;
                a1v += v1.x*x1.x + v1.y*x1.y + v1.z*x1.z + v1.w*x1.w;
            }
            float tot = redsl(a0v + a1v);
            if (sl == 0) {
                float h = lrelu(tot + bo[c] + src[jc][c]);
                if (gout) gout[c] = h;
                else      dst[jd][c] = (a0 + jd < 128) ? h : 0.f;
            }
        }
    }
}

// ---------------------------------------------------------------------------
// K1: backward-cone for one L3 column. 80 blocks (b = bid/10, i = bid%10),
// own abs col = 18 + 27*(i>>1) + (i&1)  -> {18,19,45,46,72,73,99,100,126,127}.
// Scratch coords j: abs = a0 + j, a0 = own-13; own at j=13.
// setup j in [0,27); L1 (d=1) dst {1,4,..,25}; L2 (d=3) dst {4,13,22};
// L3 (d=9) dst {13} -> l3c[b][i][:]. Exact (deepest reach abs >= 5).
// ---------------------------------------------------------------------------
__global__ void __launch_bounds__(512) k_cone(
        const float* __restrict__ x,
        const float* __restrict__ embed_w,
        const float* __restrict__ posamp_w,
        const float* __restrict__ posamp_b,
        const float* __restrict__ reduce_w,
        const float* __restrict__ reduce_b,
        const float* __restrict__ dil_w,
        const float* __restrict__ dil_b,
        const float* __restrict__ one_w,
        const float* __restrict__ one_b,
        float* __restrict__ l3c)
{
    const int bid = blockIdx.x;
    const int b   = bid / 10;
    const int i   = bid - b * 10;
    const int own = 18 + 27 * (i >> 1) + (i & 1);
    const int a0  = own - 13;
    const int tid = threadIdx.x;
    const int c   = tid >> 2;
    const int sl  = tid & 3;
    const int sl2 = 2 * sl;

    __shared__ float A[28][CCH];           // 14.3 KB
    __shared__ float B[28][CCH];           // 14.3 KB
    __shared__ float cat[27][2 * CCH];     // 27.6 KB
    __shared__ float ybuf[9][CCH];         //  4.6 KB

    // ---- fill concat for all 27 cols ----
    const float* xb = x + b * 4 * TLEN;
    for (int v = tid; v < 27 * 256; v += 512) {
        int p  = v >> 8;
        int ch = v & 255;
        int ab = a0 + p;
        float val = 0.f;
        if (ab < 128) {
            int t = (TLEN - 128) + ab;
            if (ch < CCH) {
                int idx = (int)xb[t];            // atom id (exact int in f32)
                val = embed_w[idx * CCH + ch];
            } else {
                int cc = ch - CCH;
                val = posamp_w[2*cc] * xb[TLEN + t]
                    + posamp_w[2*cc+1] * xb[2*TLEN + t] + posamp_b[cc];
            }
        }
        cat[p][ch] = val;
    }
    // weight quarter (rotated for bank-stagger)
    const float4* rw = (const float4*)(reduce_w + c * (2 * CCH) + sl * 64);
    float4 RW[16];
    #pragma unroll
    for (int j = 0; j < 16; ++j) RW[j] = rw[(j + sl2) & 15];
    __syncthreads();

    // ---- setup reduce: A[s] for s in [0,27) ----
    for (int s = 0; s < 27; ++s) {
        const float* sc = cat[s] + sl * 64;
        float p0 = 0.f, p1 = 0.f;
        #pragma unroll
        for (int g = 0; g < 16; g += 2) {
            int gr0 = ((g     + sl2) & 15) * 4;
            int gr1 = ((g + 1 + sl2) & 15) * 4;
            float4 x0 = *(const float4*)(sc + gr0);
            float4 x1 = *(const float4*)(sc + gr1);
            float4 w0 = RW[g], w1 = RW[g+1];
            p0 += w0.x*x0.x + w0.y*x0.y + w0.z*x0.z + w0.w*x0.w;
            p1 += w1.x*x1.x + w1.y*x1.y + w1.z*x1.z + w1.w*x1.w;
        }
        float tot = redsl(p0 + p1);
        if (sl == 0) A[s][c] = (a0 + s < 128) ? tot + reduce_b[c] : 0.f;
    }

    // ---- L1 (d=1): A -> B, dst {1,4,7,10,13,16,19,22,25} ----
    conv_block(A, B, nullptr,
               PK9(0,3,6,9,12,15,18,21,24),
               PK9(1,4,7,10,13,16,19,22,25),
               PK9(2,5,8,11,14,17,20,23,26),
               PK9(1,4,7,10,13,16,19,22,25), 9, a0,
               dil_w, dil_b, one_w, one_b, ybuf, c, sl);
    // ---- L2 (d=3): B -> A, dst {4,13,22} ----
    conv_block(B, A, nullptr,
               PK3(1,10,19), PK3(4,13,22), PK3(7,16,25), PK3(4,13,22), 3, a0,
               dil_w + (size_t)1 * CCH * CCH * 3, dil_b + CCH,
               one_w + (size_t)1 * CCH * CCH, one_b + CCH, ybuf, c, sl);
    // ---- L3 (d=9): A -> global l3c[b][i] ----
    conv_block(A, A, l3c + (size_t)(b * 10 + i) * CCH,
               PK1(4), PK1(13), PK1(22), PK1(13), 1, a0,
               dil_w + (size_t)2 * CCH * CCH * 3, dil_b + 2 * CCH,
               one_w + (size_t)2 * CCH * CCH, one_b + 2 * CCH, ybuf, c, sl);
}

// ---------------------------------------------------------------------------
// K2: L4 (d=27) {45,46,126,127} -> L5 (d=81) {126,127} -> L6 (d=1) {127}
// -> MLP heads. 64 blocks (b = bid>>3, g = bid&7); each block recomputes the
// tail, then does atom rows [g*448, g*448+448).
// l3c index map: 0:18 1:19 2:45 3:46 4:72 5:73 6:99 7:100 8:126 9:127.
// ---------------------------------------------------------------------------
__global__ void __launch_bounds__(512) k_tail(
        const float* __restrict__ l3c,
        const float* __restrict__ dil_w,
        const float* __restrict__ dil_b,
        const float* __restrict__ one_w,
        const float* __restrict__ one_b,
        const float* __restrict__ aw1, const float* __restrict__ ab1,
        const float* __restrict__ aw2, const float* __restrict__ ab2,
        const float* __restrict__ aw3, const float* __restrict__ ab3,
        const float* __restrict__ pw1, const float* __restrict__ pb1,
        const float* __restrict__ pw2, const float* __restrict__ pb2,
        const float* __restrict__ pw3, const float* __restrict__ pb3,
        float* __restrict__ out)
{
    const int bid = blockIdx.x;
    const int b   = bid >> 3;
    const int g   = bid & 7;
    const int tid = threadIdx.x;
    const int c   = tid >> 2;
    const int sl  = tid & 3;

    __shared__ float A2[11][CCH];          // 10 L3 cols + Z(10)
    __shared__ float B2[5][CCH];           // l4 {45,46,126,127} + Z(4)
    __shared__ float C2[3][CCH];           // l5 {126,127} + Z(2)
    __shared__ float HF[CCH];              // l6 {127}
    __shared__ float ybuf[4][CCH];
    __shared__ float h1a[CCH], h2a[CCH], h1p[CCH], h2p[CCH];

    if (tid < CCH) { A2[10][tid] = 0.f; B2[4][tid] = 0.f; C2[2][tid] = 0.f; }
    if (tid < 320) {
        int col = tid >> 5, f4 = tid & 31;
        *(float4*)&A2[col][f4 * 4] =
            *(const float4*)(l3c + (size_t)(b * 10 + col) * CCH + f4 * 4);
    }

    // L4 (d=27): dst {45,46,126,127}; 45:{18,45,72} 46:{19,46,73}
    // 126:{99,126,Z} 127:{100,127,Z}
    conv_block(A2, B2, nullptr,
               PK4(0,1,6,7), PK4(2,3,8,9), PK4(4,5,10,10), PK4(0,1,2,3),
               4, -1000,
               dil_w + (size_t)3 * CCH * CCH * 3, dil_b + 3 * CCH,
               one_w + (size_t)3 * CCH * CCH, one_b + 3 * CCH, ybuf, c, sl);
    // L5 (d=81): 126:{45,126,Z} 127:{46,127,Z}
    conv_block(B2, C2, nullptr,
               PK2(0,1), PK2(2,3), PK2(4,4), PK2(0,1), 2, -1000,
               dil_w + (size_t)4 * CCH * CCH * 3, dil_b + 4 * CCH,
               one_w + (size_t)4 * CCH * CCH, one_b + 4 * CCH, ybuf, c, sl);
    // L6 (d=1): 127:{126,127,Z}
    conv_block(C2, C2, HF,
               PK1(0), PK1(1), PK1(2), PK1(0), 1, -1000,
               dil_w + (size_t)5 * CCH * CCH * 3, dil_b + 5 * CCH,
               one_w + (size_t)5 * CCH * CCH, one_b + 5 * CCH, ybuf, c, sl);
    __syncthreads();

    // ---- MLP hidden layers (atom rows on tid<128, pa rows on tid<256) ----
    if (tid < CCH) {
        const float4* r = (const float4*)(aw1 + tid * CCH);
        float s0 = 0.f, s1 = 0.f, s2 = 0.f, s3 = 0.f;
        #pragma unroll
        for (int k = 0; k < 32; k += 4) {
            float4 w0 = r[k], w1 = r[k+1], w2 = r[k+2], w3 = r[k+3];
            s0 += w0.x*HF[4*k]    + w0.y*HF[4*k+1]  + w0.z*HF[4*k+2]  + w0.w*HF[4*k+3];
            s1 += w1.x*HF[4*k+4]  + w1.y*HF[4*k+5]  + w1.z*HF[4*k+6]  + w1.w*HF[4*k+7];
            s2 += w2.x*HF[4*k+8]  + w2.y*HF[4*k+9]  + w2.z*HF[4*k+10] + w2.w*HF[4*k+11];
            s3 += w3.x*HF[4*k+12] + w3.y*HF[4*k+13] + w3.z*HF[4*k+14] + w3.w*HF[4*k+15];
        }
        h1a[tid] = lrelu(s0 + s1 + s2 + s3 + ab1[tid]);
    } else if (tid < 2 * CCH) {
        int cc = tid - CCH;
        const float4* r = (const float4*)(pw1 + cc * CCH);
        float s0 = 0.f, s1 = 0.f, s2 = 0.f, s3 = 0.f;
        #pragma unroll
        for (int k = 0; k < 32; k += 4) {
            float4 w0 = r[k], w1 = r[k+1], w2 = r[k+2], w3 = r[k+3];
            s0 += w0.x*HF[4*k]    + w0.y*HF[4*k+1]  + w0.z*HF[4*k+2]  + w0.w*HF[4*k+3];
            s1 += w1.x*HF[4*k+4]  + w1.y*HF[4*k+5]  + w1.z*HF[4*k+6]  + w1.w*HF[4*k+7];
            s2 += w2.x*HF[4*k+8]  + w2.y*HF[4*k+9]  + w2.z*HF[4*k+10] + w2.w*HF[4*k+11];
            s3 += w3.x*HF[4*k+12] + w3.y*HF[4*k+13] + w3.z*HF[4*k+14] + w3.w*HF[4*k+15];
        }
        h1p[cc] = lrelu(s0 + s1 + s2 + s3 + pb1[cc]);
    }
    __syncthreads();
    if (tid < CCH) {
        const float4* r = (const float4*)(aw2 + tid * CCH);
        float s0 = 0.f, s1 = 0.f, s2 = 0.f, s3 = 0.f;
        #pragma unroll
        for (int k = 0; k < 32; k += 4) {
            float4 w0 = r[k], w1 = r[k+1], w2 = r[k+2], w3 = r[k+3];
            s0 += w0.x*h1a[4*k]    + w0.y*h1a[4*k+1]  + w0.z*h1a[4*k+2]  + w0.w*h1a[4*k+3];
            s1 += w1.x*h1a[4*k+4]  + w1.y*h1a[4*k+5]  + w1.z*h1a[4*k+6]  + w1.w*h1a[4*k+7];
            s2 += w2.x*h1a[4*k+8]  + w2.y*h1a[4*k+9]  + w2.z*h1a[4*k+10] + w2.w*h1a[4*k+11];
            s3 += w3.x*h1a[4*k+12] + w3.y*h1a[4*k+13] + w3.z*h1a[4*k+14] + w3.w*h1a[4*k+15];
        }
        h2a[tid] = lrelu(s0 + s1 + s2 + s3 + ab2[tid]);
    } else if (tid < 2 * CCH) {
        int cc = tid - CCH;
        const float4* r = (const float4*)(pw2 + cc * CCH);
        float s0 = 0.f, s1 = 0.f, s2 = 0.f, s3 = 0.f;
        #pragma unroll
        for (int k = 0; k < 32; k += 4) {
            float4 w0 = r[k], w1 = r[k+1], w2 = r[k+2], w3 = r[k+3];
            s0 += w0.x*h1p[4*k]    + w0.y*h1p[4*k+1]  + w0.z*h1p[4*k+2]  + w0.w*h1p[4*k+3];
            s1 += w1.x*h1p[4*k+4]  + w1.y*h1p[4*k+5]  + w1.z*h1p[4*k+6]  + w1.w*h1p[4*k+7];
            s2 += w2.x*h1p[4*k+8]  + w2.y*h1p[4*k+9]  + w2.z*h1p[4*k+10] + w2.w*h1p[4*k+11];
            s3 += w3.x*h1p[4*k+12] + w3.y*h1p[4*k+13] + w3.z*h1p[4*k+14] + w3.w*h1p[4*k+15];
        }
        h2p[cc] = lrelu(s0 + s1 + s2 + s3 + pb2[cc]);
    }
    __syncthreads();

    // ---- atom logits: rows [g*448, g*448+448) ----
    if (tid < 448) {
        int row = g * 448 + tid;
        const float4* r = (const float4*)(aw3 + (size_t)row * CCH);
        float s0 = 0.f, s1 = 0.f, s2 = 0.f, s3 = 0.f;
        #pragma unroll
        for (int k = 0; k < 32; k += 4) {
            float4 w0 = r[k], w1 = r[k+1], w2 = r[k+2], w3 = r[k+3];
            s0 += w0.x*h2a[4*k]    + w0.y*h2a[4*k+1]  + w0.z*h2a[4*k+2]  + w0.w*h2a[4*k+3];
            s1 += w1.x*h2a[4*k+4]  + w1.y*h2a[4*k+5]  + w1.z*h2a[4*k+6]  + w1.w*h2a[4*k+7];
            s2 += w2.x*h2a[4*k+8]  + w2.y*h2a[4*k+9]  + w2.z*h2a[4*k+10] + w2.w*h2a[4*k+11];
            s3 += w3.x*h2a[4*k+12] + w3.y*h2a[4*k+13] + w3.z*h2a[4*k+14] + w3.w*h2a[4*k+15];
        }
        out[b * NATOMS + row] = s0 + s1 + s2 + s3 + ab3[row];
    } else if (g == 0 && tid < 450) {
        int cc = tid - 448;
        const float4* r = (const float4*)(pw3 + cc * CCH);
        float s0 = 0.f, s1 = 0.f;
        #pragma unroll
        for (int k = 0; k < 32; k += 2) {
            float4 w0 = r[k], w1 = r[k+1];
            s0 += w0.x*h2p[4*k]   + w0.y*h2p[4*k+1] + w0.z*h2p[4*k+2] + w0.w*h2p[4*k+3];
            s1 += w1.x*h2p[4*k+4] + w1.y*h2p[4*k+5] + w1.z*h2p[4*k+6] + w1.w*h2p[4*k+7];
        }
        out[NBATCH * NATOMS + b * 2 + cc] = s0 + s1 + pb3[cc];
    }
}

// ---------------------------------------------------------------------------
extern "C" void kernel_launch(void* const* d_in, const int* in_sizes, int n_in,
                              void* d_out, int out_size, void* d_ws, size_t ws_size,
                              hipStream_t stream)
{
    const float* x        = (const float*)d_in[0];
    const float* embed_w  = (const float*)d_in[1];
    const float* posamp_w = (const float*)d_in[2];
    const float* posamp_b = (const float*)d_in[3];
    const float* reduce_w = (const float*)d_in[4];
    const float* reduce_b = (const float*)d_in[5];
    const float* dil_w    = (const float*)d_in[6];
    const float* dil_b    = (const float*)d_in[7];
    const float* one_w    = (const float*)d_in[8];
    const float* one_b    = (const float*)d_in[9];
    const float* aw1 = (const float*)d_in[10]; const float* ab1 = (const float*)d_in[11];
    const float* aw2 = (const float*)d_in[12]; const float* ab2 = (const float*)d_in[13];
    const float* aw3 = (const float*)d_in[14]; const float* ab3 = (const float*)d_in[15];
    const float* pw1 = (const float*)d_in[16]; const float* pb1 = (const float*)d_in[17];
    const float* pw2 = (const float*)d_in[18]; const float* pb2 = (const float*)d_in[19];
    const float* pw3 = (const float*)d_in[20]; const float* pb3 = (const float*)d_in[21];

    float* l3c = (float*)d_ws;     // [8][10][128] f32 = 40 KB

    k_cone<<<dim3(80), dim3(512), 0, stream>>>(
        x, embed_w, posamp_w, posamp_b, reduce_w, reduce_b,
        dil_w, dil_b, one_w, one_b, l3c);

    k_tail<<<dim3(64), dim3(512), 0, stream>>>(
        l3c, dil_w, dil_b, one_w, one_b,
        aw1, ab1, aw2, ab2, aw3, ab3,
        pw1, pb1, pw2, pb2, pw3, pb3, (float*)d_out);
}

// Round 7
// 68.549 us; speedup vs baseline: 4.2035x; 1.1491x over previous
//
#include <hip/hip_runtime.h>

#define CCH 128      // channels
#define TLEN 2048
#define NBATCH 8
#define NATOMS 3584
#define NEG 0.2f
typedef unsigned long long ull;

// 7-bit packed index lists (up to 9 slots in 63 bits)
#define PK1(a) ((ull)(a))
#define PK2(a,b) (PK1(a)|((ull)(b)<<7))
#define PK3(a,b,c) (PK2(a,b)|((ull)(c)<<14))
#define PK4(a,b,c,d) (PK3(a,b,c)|((ull)(d)<<21))
#define PK9(a,b,c,d,e,f,g,h,i) (PK4(a,b,c,d)|((ull)(e)<<28)| \
    ((ull)(f)<<35)|((ull)(g)<<42)|((ull)(h)<<49)|((ull)(i)<<56))

__device__ __forceinline__ float lrelu(float v) { return v >= 0.f ? v : NEG * v; }
__device__ __forceinline__ float dot4(float4 w, float4 x) {
    return w.x * x.x + w.y * x.y + w.z * x.z + w.w * x.w;
}

// Reduce 4 accumulators over the 16 K-split lanes (tid = g*16+s).
// Returns the full sum of acc_{s&3}; lane s holds out-ch 4g + (s&3).
__device__ __forceinline__ float red16x4(float a0, float a1, float a2, float a3, int s) {
    a0 += __shfl_xor(a0, 8); a1 += __shfl_xor(a1, 8);
    a2 += __shfl_xor(a2, 8); a3 += __shfl_xor(a3, 8);
    a0 += __shfl_xor(a0, 4); a1 += __shfl_xor(a1, 4);
    a2 += __shfl_xor(a2, 4); a3 += __shfl_xor(a3, 4);
    float u0 = (s & 2) ? a2 : a0;
    float v0 = (s & 2) ? a0 : a2;
    u0 += __shfl_xor(v0, 2);
    float u1 = (s & 2) ? a3 : a1;
    float v1 = (s & 2) ? a1 : a3;
    u1 += __shfl_xor(v1, 2);
    float w  = (s & 1) ? u1 : u0;
    float vv = (s & 1) ? u0 : u1;
    w += __shfl_xor(vv, 1);
    return w;
}

// One residual dilated block over nb (<=9) scratch columns.
// R=4 out-ch/thread (rows 4g..4g+3), S=16 K-split: lane s owns in-ch chunks
// {4s..4s+3, 64+4s..64+4s+3} (strided -> conflict-free LDS banks).
// W layout [C][128 in][3 tap]: i-chunk s = 3 float4 at f4-index 3s.
// pm/pc/pp/pd: packed src(-d), src(0)=residual, src(+d), dst columns.
// dst col forced 0 when a0+jd >= 128; gout!=null (nb==1): write gout[ch].
__device__ __forceinline__ void conv4(
        const float (*src)[CCH], float (*dst)[CCH], float* gout,
        ull pm, ull pc, ull pp, ull pd, int nb, int a0,
        const float* __restrict__ Wd, const float* __restrict__ bd,
        const float* __restrict__ Wo, const float* __restrict__ bo,
        float (*ybuf)[CCH], int g, int s)
{
    const int ch = 4 * g + (s & 3);
    const float myBd = bd[ch];
    const float myBo = bo[ch];
    float4 W[24], V[8];
    {
        const float4* Wr = (const float4*)Wd + (size_t)(4 * g) * 96;
        #pragma unroll
        for (int r = 0; r < 4; ++r)
            #pragma unroll
            for (int j = 0; j < 3; ++j) {
                W[r * 6 + j]     = Wr[r * 96 + 3 * s + j];
                W[r * 6 + 3 + j] = Wr[r * 96 + 3 * s + 48 + j];
            }
        const float4* Or = (const float4*)Wo + (size_t)(4 * g) * 32;
        #pragma unroll
        for (int r = 0; r < 4; ++r) {
            V[r * 2]     = Or[r * 32 + s];
            V[r * 2 + 1] = Or[r * 32 + s + 16];
        }
    }
    __syncthreads();                     // src + ybuf free
    for (int t = 0; t < nb; ++t) {
        const float* fm = src[(int)((pm >> (7 * t)) & 127)];
        const float* fc = src[(int)((pc >> (7 * t)) & 127)];
        const float* fp = src[(int)((pp >> (7 * t)) & 127)];
        float4 m0 = *(const float4*)(fm + 4 * s);
        float4 m1 = *(const float4*)(fm + 4 * s + 64);
        float4 c0 = *(const float4*)(fc + 4 * s);
        float4 c1 = *(const float4*)(fc + 4 * s + 64);
        float4 p0 = *(const float4*)(fp + 4 * s);
        float4 p1 = *(const float4*)(fp + 4 * s + 64);
        float acc[4];
        #pragma unroll
        for (int r = 0; r < 4; ++r) {
            float4 wA = W[r*6+0], wB = W[r*6+1], wC = W[r*6+2];
            float a = wA.x*m0.x + wA.y*c0.x + wA.z*p0.x + wA.w*m0.y
                    + wB.x*c0.y + wB.y*p0.y + wB.z*m0.z + wB.w*c0.z
                    + wC.x*p0.z + wC.y*m0.w + wC.z*c0.w + wC.w*p0.w;
            float4 wD = W[r*6+3], wE = W[r*6+4], wF = W[r*6+5];
            float b2 = wD.x*m1.x + wD.y*c1.x + wD.z*p1.x + wD.w*m1.y
                     + wE.x*c1.y + wE.y*p1.y + wE.z*m1.z + wE.w*c1.z
                     + wF.x*p1.z + wF.y*m1.w + wF.z*c1.w + wF.w*p1.w;
            acc[r] = a + b2;
        }
        float tot = red16x4(acc[0], acc[1], acc[2], acc[3], s);
        if (s < 4) ybuf[t][ch] = tot + myBd;
    }
    __syncthreads();                     // ybuf ready
    for (int t = 0; t < nb; ++t) {
        int jc = (int)((pc >> (7 * t)) & 127);
        int jd = (int)((pd >> (7 * t)) & 127);
        const float* y = ybuf[t];
        float4 y0 = *(const float4*)(y + 4 * s);
        float4 y1 = *(const float4*)(y + 4 * s + 64);
        float a0_ = dot4(V[0], y0) + dot4(V[1], y1);
        float a1_ = dot4(V[2], y0) + dot4(V[3], y1);
        float a2_ = dot4(V[4], y0) + dot4(V[5], y1);
        float a3_ = dot4(V[6], y0) + dot4(V[7], y1);
        float tot = red16x4(a0_, a1_, a2_, a3_, s);
        if (s < 4) {
            float h = lrelu(tot + myBo + src[jc][ch]);
            if (gout) gout[ch] = h;
            else      dst[jd][ch] = (a0 + jd < 128) ? h : 0.f;
        }
    }
}

// K=128 matvec stage (MLP hidden layer), same R=4/S=16 mapping, lrelu.
__device__ __forceinline__ void mlp4(
        const float* hin, float* hout,
        const float* __restrict__ w, const float* __restrict__ bv,
        int g, int s)
{
    const int ch = 4 * g + (s & 3);
    const float myB = bv[ch];
    float4 V[8];
    const float4* r = (const float4*)w + (size_t)(4 * g) * 32;
    #pragma unroll
    for (int rr = 0; rr < 4; ++rr) {
        V[rr * 2]     = r[rr * 32 + s];
        V[rr * 2 + 1] = r[rr * 32 + s + 16];
    }
    __syncthreads();                     // hin ready
    float4 x0 = *(const float4*)(hin + 4 * s);
    float4 x1 = *(const float4*)(hin + 4 * s + 64);
    float a0_ = dot4(V[0], x0) + dot4(V[1], x1);
    float a1_ = dot4(V[2], x0) + dot4(V[3], x1);
    float a2_ = dot4(V[4], x0) + dot4(V[5], x1);
    float a3_ = dot4(V[6], x0) + dot4(V[7], x1);
    float tot = red16x4(a0_, a1_, a2_, a3_, s);
    if (s < 4) hout[ch] = lrelu(tot + myB);
}

// ---------------------------------------------------------------------------
// K1: backward-cone for one L3 column. 80 blocks (b = bid/10, i = bid%10),
// own abs col = 18 + 27*(i>>1) + (i&1) -> {18,19,45,46,72,73,99,100,126,127}.
// Scratch j: abs = a0 + j, a0 = own-13. setup j in [0,27); L1 (d=1) dst
// {1,4,..,25}; L2 (d=3) dst {4,13,22}; L3 (d=9) dst {13} -> l3c[b][i][:].
// Exact (deepest reach abs >= 5). Geometry verified R5/R6.
// ---------------------------------------------------------------------------
__global__ void __launch_bounds__(512, 2) k_cone(
        const float* __restrict__ x,
        const float* __restrict__ embed_w,
        const float* __restrict__ posamp_w,
        const float* __restrict__ posamp_b,
        const float* __restrict__ reduce_w,
        const float* __restrict__ reduce_b,
        const float* __restrict__ dil_w,
        const float* __restrict__ dil_b,
        const float* __restrict__ one_w,
        const float* __restrict__ one_b,
        float* __restrict__ l3c)
{
    const int bid = blockIdx.x;
    const int b   = bid / 10;
    const int i   = bid - b * 10;
    const int own = 18 + 27 * (i >> 1) + (i & 1);
    const int a0  = own - 13;
    const int tid = threadIdx.x;
    const int g   = tid >> 4;
    const int s   = tid & 15;
    const int ch  = 4 * g + (s & 3);

    __shared__ float A[28][CCH];           // 14.3 KB
    __shared__ float B[28][CCH];           // 14.3 KB
    __shared__ float cat[27][2 * CCH];     // 27.6 KB
    __shared__ float ybuf[9][CCH];         //  4.6 KB

    // ---- fill concat for all 27 cols ----
    const float* xb = x + b * 4 * TLEN;
    for (int v = tid; v < 27 * 256; v += 512) {
        int p   = v >> 8;
        int chv = v & 255;
        int ab  = a0 + p;
        float val = 0.f;
        if (ab < 128) {
            int t = (TLEN - 128) + ab;
            if (chv < CCH) {
                int idx = (int)xb[t];            // atom id (exact int in f32)
                val = embed_w[idx * CCH + chv];
            } else {
                int cc = chv - CCH;
                val = posamp_w[2 * cc] * xb[TLEN + t]
                    + posamp_w[2 * cc + 1] * xb[2 * TLEN + t] + posamp_b[cc];
            }
        }
        cat[p][chv] = val;
    }
    // setup weights: rows 4g..4g+3, chunks {s, s+16, s+32, s+48}
    float4 RW[16];
    const float4* rw = (const float4*)reduce_w + (size_t)(4 * g) * 64;
    #pragma unroll
    for (int r = 0; r < 4; ++r)
        #pragma unroll
        for (int j = 0; j < 4; ++j)
            RW[r * 4 + j] = rw[r * 64 + s + 16 * j];
    const float rb = reduce_b[ch];
    __syncthreads();

    // ---- setup reduce: A[t] for t in [0,27) ----
    for (int t = 0; t < 27; ++t) {
        const float* sc = cat[t];
        float4 x0 = *(const float4*)(sc + 4 * s);
        float4 x1 = *(const float4*)(sc + 4 * s + 64);
        float4 x2 = *(const float4*)(sc + 4 * s + 128);
        float4 x3 = *(const float4*)(sc + 4 * s + 192);
        float a0_ = dot4(RW[0], x0) + dot4(RW[1], x1) + dot4(RW[2], x2) + dot4(RW[3], x3);
        float a1_ = dot4(RW[4], x0) + dot4(RW[5], x1) + dot4(RW[6], x2) + dot4(RW[7], x3);
        float a2_ = dot4(RW[8], x0) + dot4(RW[9], x1) + dot4(RW[10], x2) + dot4(RW[11], x3);
        float a3_ = dot4(RW[12], x0) + dot4(RW[13], x1) + dot4(RW[14], x2) + dot4(RW[15], x3);
        float tot = red16x4(a0_, a1_, a2_, a3_, s);
        if (s < 4) A[t][ch] = (a0 + t < 128) ? tot + rb : 0.f;
    }

    // ---- L1 (d=1): A -> B, dst {1,4,7,10,13,16,19,22,25} ----
    conv4(A, B, nullptr,
          PK9(0,3,6,9,12,15,18,21,24),
          PK9(1,4,7,10,13,16,19,22,25),
          PK9(2,5,8,11,14,17,20,23,26),
          PK9(1,4,7,10,13,16,19,22,25), 9, a0,
          dil_w, dil_b, one_w, one_b, ybuf, g, s);
    // ---- L2 (d=3): B -> A, dst {4,13,22} ----
    conv4(B, A, nullptr,
          PK3(1,10,19), PK3(4,13,22), PK3(7,16,25), PK3(4,13,22), 3, a0,
          dil_w + (size_t)1 * CCH * CCH * 3, dil_b + CCH,
          one_w + (size_t)1 * CCH * CCH, one_b + CCH, ybuf, g, s);
    // ---- L3 (d=9): A -> global l3c[b][i] ----
    conv4(A, A, l3c + (size_t)(b * 10 + i) * CCH,
          PK1(4), PK1(13), PK1(22), PK1(13), 1, a0,
          dil_w + (size_t)2 * CCH * CCH * 3, dil_b + 2 * CCH,
          one_w + (size_t)2 * CCH * CCH, one_b + 2 * CCH, ybuf, g, s);
}

// ---------------------------------------------------------------------------
// K2: per-batch tail: L4 (d=27) {45,46,126,127} -> L5 (d=81) {126,127} ->
// L6 (d=1) {127} -> MLP hidden layers -> h2a (to ws) + pa head (to out).
// 8 blocks. l3c map: 0:18 1:19 2:45 3:46 4:72 5:73 6:99 7:100 8:126 9:127.
// ---------------------------------------------------------------------------
__global__ void __launch_bounds__(512, 2) k_tail(
        const float* __restrict__ l3c,
        const float* __restrict__ dil_w,
        const float* __restrict__ dil_b,
        const float* __restrict__ one_w,
        const float* __restrict__ one_b,
        const float* __restrict__ aw1, const float* __restrict__ ab1,
        const float* __restrict__ aw2, const float* __restrict__ ab2,
        const float* __restrict__ pw1, const float* __restrict__ pb1,
        const float* __restrict__ pw2, const float* __restrict__ pb2,
        const float* __restrict__ pw3, const float* __restrict__ pb3,
        float* __restrict__ h2w,
        float* __restrict__ out)
{
    const int b   = blockIdx.x;
    const int tid = threadIdx.x;
    const int g   = tid >> 4;
    const int s   = tid & 15;

    __shared__ float A2[11][CCH];          // 10 L3 cols + Z(10)
    __shared__ float B2[5][CCH];           // L4 {45,46,126,127} + Z(4)
    __shared__ float C2[3][CCH];           // L5 {126,127} + Z(2)
    __shared__ float HF[CCH];              // L6 {127}
    __shared__ float ybuf[4][CCH];
    __shared__ float h1a[CCH], h1p[CCH], h2p[CCH];

    if (tid < CCH) { A2[10][tid] = 0.f; B2[4][tid] = 0.f; C2[2][tid] = 0.f; }
    if (tid < 320) {
        int col = tid >> 5, f4i = tid & 31;
        *(float4*)&A2[col][f4i * 4] =
            *(const float4*)(l3c + (size_t)(b * 10 + col) * CCH + f4i * 4);
    }

    // L4: 45:{18,45,72} 46:{19,46,73} 126:{99,126,Z} 127:{100,127,Z}
    conv4(A2, B2, nullptr,
          PK4(0,1,6,7), PK4(2,3,8,9), PK4(4,5,10,10), PK4(0,1,2,3), 4, -1000,
          dil_w + (size_t)3 * CCH * CCH * 3, dil_b + 3 * CCH,
          one_w + (size_t)3 * CCH * CCH, one_b + 3 * CCH, ybuf, g, s);
    // L5: 126:{45,126,Z} 127:{46,127,Z}
    conv4(B2, C2, nullptr,
          PK2(0,1), PK2(2,3), PK2(4,4), PK2(0,1), 2, -1000,
          dil_w + (size_t)4 * CCH * CCH * 3, dil_b + 4 * CCH,
          one_w + (size_t)4 * CCH * CCH, one_b + 4 * CCH, ybuf, g, s);
    // L6: 127:{126,127,Z} -> HF
    conv4(C2, C2, HF,
          PK1(0), PK1(1), PK1(2), PK1(0), 1, -1000,
          dil_w + (size_t)5 * CCH * CCH * 3, dil_b + 5 * CCH,
          one_w + (size_t)5 * CCH * CCH, one_b + 5 * CCH, ybuf, g, s);

    // ---- MLP hidden layers ----
    mlp4(HF, h1a, aw1, ab1, g, s);
    mlp4(HF, h1p, pw1, pb1, g, s);
    mlp4(h1a, h2w + b * CCH, aw2, ab2, g, s);   // atom h2 -> global ws
    mlp4(h1p, h2p, pw2, pb2, g, s);
    __syncthreads();

    // ---- pa head: 2 outputs, K=128 over 64 lanes ----
    if (tid < 64) {
        int row = tid >> 5, q = tid & 31;
        float4 w4 = *(const float4*)(pw3 + row * CCH + 4 * q);
        float4 xv = *(const float4*)(h2p + 4 * q);
        float acc = dot4(w4, xv);
        acc += __shfl_xor(acc, 1);
        acc += __shfl_xor(acc, 2);
        acc += __shfl_xor(acc, 4);
        acc += __shfl_xor(acc, 8);
        acc += __shfl_xor(acc, 16);
        if (q == 0) out[NBATCH * NATOMS + b * 2 + row] = acc + pb3[row];
    }
}

// ---------------------------------------------------------------------------
// K3: atom logits. grid (7, 8) x 512; block does rows [jx*512, jx*512+512).
// ---------------------------------------------------------------------------
__global__ void __launch_bounds__(512) k_head(
        const float* __restrict__ h2w,
        const float* __restrict__ aw3, const float* __restrict__ ab3,
        float* __restrict__ out)
{
    const int b   = blockIdx.y;
    const int row = blockIdx.x * 512 + threadIdx.x;
    __shared__ float hs[CCH];
    if (threadIdx.x < 32)
        *(float4*)&hs[threadIdx.x * 4] =
            *(const float4*)(h2w + b * CCH + threadIdx.x * 4);
    __syncthreads();

    const float4* r = (const float4*)(aw3 + (size_t)row * CCH);
    float s0 = 0.f, s1 = 0.f, s2 = 0.f, s3 = 0.f;
    #pragma unroll
    for (int k = 0; k < 32; k += 4) {
        s0 += dot4(r[k],     *(const float4*)&hs[4 * k]);
        s1 += dot4(r[k + 1], *(const float4*)&hs[4 * k + 4]);
        s2 += dot4(r[k + 2], *(const float4*)&hs[4 * k + 8]);
        s3 += dot4(r[k + 3], *(const float4*)&hs[4 * k + 12]);
    }
    out[b * NATOMS + row] = s0 + s1 + s2 + s3 + ab3[row];
}

// ---------------------------------------------------------------------------
extern "C" void kernel_launch(void* const* d_in, const int* in_sizes, int n_in,
                              void* d_out, int out_size, void* d_ws, size_t ws_size,
                              hipStream_t stream)
{
    const float* x        = (const float*)d_in[0];
    const float* embed_w  = (const float*)d_in[1];
    const float* posamp_w = (const float*)d_in[2];
    const float* posamp_b = (const float*)d_in[3];
    const float* reduce_w = (const float*)d_in[4];
    const float* reduce_b = (const float*)d_in[5];
    const float* dil_w    = (const float*)d_in[6];
    const float* dil_b    = (const float*)d_in[7];
    const float* one_w    = (const float*)d_in[8];
    const float* one_b    = (const float*)d_in[9];
    const float* aw1 = (const float*)d_in[10]; const float* ab1 = (const float*)d_in[11];
    const float* aw2 = (const float*)d_in[12]; const float* ab2 = (const float*)d_in[13];
    const float* aw3 = (const float*)d_in[14]; const float* ab3 = (const float*)d_in[15];
    const float* pw1 = (const float*)d_in[16]; const float* pb1 = (const float*)d_in[17];
    const float* pw2 = (const float*)d_in[18]; const float* pb2 = (const float*)d_in[19];
    const float* pw3 = (const float*)d_in[20]; const float* pb3 = (const float*)d_in[21];

    float* l3c = (float*)d_ws;                 // [8][10][128] = 40 KB
    float* h2w = l3c + NBATCH * 10 * CCH;      // [8][128]

    k_cone<<<dim3(80), dim3(512), 0, stream>>>(
        x, embed_w, posamp_w, posamp_b, reduce_w, reduce_b,
        dil_w, dil_b, one_w, one_b, l3c);

    k_tail<<<dim3(NBATCH), dim3(512), 0, stream>>>(
        l3c, dil_w, dil_b, one_w, one_b,
        aw1, ab1, aw2, ab2, pw1, pb1, pw2, pb2, pw3, pb3,
        h2w, (float*)d_out);

    k_head<<<dim3(7, NBATCH), dim3(512), 0, stream>>>(
        h2w, aw3, ab3, (float*)d_out);
}

// Round 8
// 61.995 us; speedup vs baseline: 4.6479x; 1.1057x over previous
//
#include <hip/hip_runtime.h>

#define CCH 128      // channels
#define TLEN 2048
#define NBATCH 8
#define NATOMS 3584
#define NEG 0.2f
typedef unsigned long long ull;

// 7-bit packed index lists (up to 9 slots in 63 bits)
#define PK1(a) ((ull)(a))
#define PK2(a,b) (PK1(a)|((ull)(b)<<7))
#define PK3(a,b,c) (PK2(a,b)|((ull)(c)<<14))
#define PK4(a,b,c,d) (PK3(a,b,c)|((ull)(d)<<21))
#define PK5(a,b,c,d,e) (PK4(a,b,c,d)|((ull)(e)<<28))

// Per-batch unique L2 columns (union of {o-9,o,o+9} for L3 cols
// o in {18,19,45,46,72,73,99,100,126,127}), sorted:
__device__ const int g_l2cols[28] = {
    9,10,18,19,27,28,36,37,45,46,54,55,63,64,
    72,73,81,82,90,91,99,100,108,109,117,118,126,127};

__device__ __forceinline__ float lrelu(float v) { return v >= 0.f ? v : NEG * v; }
__device__ __forceinline__ float dot4(float4 w, float4 x) {
    return w.x * x.x + w.y * x.y + w.z * x.z + w.w * x.w;
}

// Reduce 4 accumulators over the 16 K-split lanes (tid = g*16+s).
// Returns the full sum of acc_{s&3}; lane s holds out-ch 4g + (s&3).
__device__ __forceinline__ float red16x4(float a0, float a1, float a2, float a3, int s) {
    a0 += __shfl_xor(a0, 8); a1 += __shfl_xor(a1, 8);
    a2 += __shfl_xor(a2, 8); a3 += __shfl_xor(a3, 8);
    a0 += __shfl_xor(a0, 4); a1 += __shfl_xor(a1, 4);
    a2 += __shfl_xor(a2, 4); a3 += __shfl_xor(a3, 4);
    float u0 = (s & 2) ? a2 : a0;
    float v0 = (s & 2) ? a0 : a2;
    u0 += __shfl_xor(v0, 2);
    float u1 = (s & 2) ? a3 : a1;
    float v1 = (s & 2) ? a1 : a3;
    u1 += __shfl_xor(v1, 2);
    float w  = (s & 1) ? u1 : u0;
    float vv = (s & 1) ? u0 : u1;
    w += __shfl_xor(vv, 1);
    return w;
}

// One residual dilated block over NB (compile-time) scratch columns.
// R=4 out-ch/thread (rows 4g..4g+3), S=16 K-split: lane s owns in-ch chunks
// {4s..4s+3, 64+4s..64+4s+3} (strided -> conflict-free LDS banks).
// pm/pc/pp/pd: packed src(-d), src(0)=residual, src(+d), dst columns.
// dst col forced 0 when a0+jd >= 128; gout!=null (NB==1): write gout[ch].
template<int NB>
__device__ __forceinline__ void conv4(
        const float (*src)[CCH], float (*dst)[CCH], float* gout,
        ull pm, ull pc, ull pp, ull pd, int a0,
        const float* __restrict__ Wd, const float* __restrict__ bd,
        const float* __restrict__ Wo, const float* __restrict__ bo,
        float (*ybuf)[CCH], int g, int s)
{
    const int ch = 4 * g + (s & 3);
    const float myBd = bd[ch];
    const float myBo = bo[ch];
    float4 W[24], V[8];
    {
        const float4* Wr = (const float4*)Wd + (size_t)(4 * g) * 96;
        #pragma unroll
        for (int r = 0; r < 4; ++r)
            #pragma unroll
            for (int j = 0; j < 3; ++j) {
                W[r * 6 + j]     = Wr[r * 96 + 3 * s + j];
                W[r * 6 + 3 + j] = Wr[r * 96 + 3 * s + 48 + j];
            }
        const float4* Or = (const float4*)Wo + (size_t)(4 * g) * 32;
        #pragma unroll
        for (int r = 0; r < 4; ++r) {
            V[r * 2]     = Or[r * 32 + s];
            V[r * 2 + 1] = Or[r * 32 + s + 16];
        }
    }
    __syncthreads();                     // src ready + ybuf free
    #pragma unroll
    for (int t = 0; t < NB; ++t) {
        const float* fm = src[(int)((pm >> (7 * t)) & 127)];
        const float* fc = src[(int)((pc >> (7 * t)) & 127)];
        const float* fp = src[(int)((pp >> (7 * t)) & 127)];
        float4 m0 = *(const float4*)(fm + 4 * s);
        float4 m1 = *(const float4*)(fm + 4 * s + 64);
        float4 c0 = *(const float4*)(fc + 4 * s);
        float4 c1 = *(const float4*)(fc + 4 * s + 64);
        float4 p0 = *(const float4*)(fp + 4 * s);
        float4 p1 = *(const float4*)(fp + 4 * s + 64);
        float acc[4];
        #pragma unroll
        for (int r = 0; r < 4; ++r) {
            float4 wA = W[r*6+0], wB = W[r*6+1], wC = W[r*6+2];
            float a = wA.x*m0.x + wA.y*c0.x + wA.z*p0.x + wA.w*m0.y
                    + wB.x*c0.y + wB.y*p0.y + wB.z*m0.z + wB.w*c0.z
                    + wC.x*p0.z + wC.y*m0.w + wC.z*c0.w + wC.w*p0.w;
            float4 wD = W[r*6+3], wE = W[r*6+4], wF = W[r*6+5];
            float b2 = wD.x*m1.x + wD.y*c1.x + wD.z*p1.x + wD.w*m1.y
                     + wE.x*c1.y + wE.y*p1.y + wE.z*m1.z + wE.w*c1.z
                     + wF.x*p1.z + wF.y*m1.w + wF.z*c1.w + wF.w*p1.w;
            acc[r] = a + b2;
        }
        float tot = red16x4(acc[0], acc[1], acc[2], acc[3], s);
        if (s < 4) ybuf[t][ch] = tot + myBd;
    }
    __syncthreads();                     // ybuf ready
    #pragma unroll
    for (int t = 0; t < NB; ++t) {
        int jc = (int)((pc >> (7 * t)) & 127);
        int jd = (int)((pd >> (7 * t)) & 127);
        const float* y = ybuf[t];
        float4 y0 = *(const float4*)(y + 4 * s);
        float4 y1 = *(const float4*)(y + 4 * s + 64);
        float a0_ = dot4(V[0], y0) + dot4(V[1], y1);
        float a1_ = dot4(V[2], y0) + dot4(V[3], y1);
        float a2_ = dot4(V[4], y0) + dot4(V[5], y1);
        float a3_ = dot4(V[6], y0) + dot4(V[7], y1);
        float tot = red16x4(a0_, a1_, a2_, a3_, s);
        if (s < 4) {
            float h = lrelu(tot + myBo + src[jc][ch]);
            if (gout) gout[ch] = h;
            else      dst[jd][ch] = (a0 + jd < 128) ? h : 0.f;
        }
    }
}

// K=128 matvec stage (MLP hidden layer), same R=4/S=16 mapping, lrelu.
__device__ __forceinline__ void mlp4(
        const float* hin, float* hout,
        const float* __restrict__ w, const float* __restrict__ bv,
        int g, int s)
{
    const int ch = 4 * g + (s & 3);
    const float myB = bv[ch];
    float4 V[8];
    const float4* r = (const float4*)w + (size_t)(4 * g) * 32;
    #pragma unroll
    for (int rr = 0; rr < 4; ++rr) {
        V[rr * 2]     = r[rr * 32 + s];
        V[rr * 2 + 1] = r[rr * 32 + s + 16];
    }
    __syncthreads();                     // hin ready
    float4 x0 = *(const float4*)(hin + 4 * s);
    float4 x1 = *(const float4*)(hin + 4 * s + 64);
    float a0_ = dot4(V[0], x0) + dot4(V[1], x1);
    float a1_ = dot4(V[2], x0) + dot4(V[3], x1);
    float a2_ = dot4(V[4], x0) + dot4(V[5], x1);
    float a3_ = dot4(V[6], x0) + dot4(V[7], x1);
    float tot = red16x4(a0_, a1_, a2_, a3_, s);
    if (s < 4) hout[ch] = lrelu(tot + myB);
}

// ---------------------------------------------------------------------------
// K1: mini-cone for one L2 column. grid (28, 8): i = blockIdx.x (L2-col idx),
// b = blockIdx.y. own = g_l2cols[i]; scratch j: abs = a0 + j, a0 = own-4.
// setup j in [0,9); L1 (d=1) dst {1,4,7}; L2 (d=3) dst {4} -> l2c[b][i][:].
// Exact: left reach abs >= 5 (own >= 9); right cols >= 128 zero-masked.
// ---------------------------------------------------------------------------
__global__ void __launch_bounds__(512, 2) k_cone(
        const float* __restrict__ x,
        const float* __restrict__ embed_w,
        const float* __restrict__ posamp_w,
        const float* __restrict__ posamp_b,
        const float* __restrict__ reduce_w,
        const float* __restrict__ reduce_b,
        const float* __restrict__ dil_w,
        const float* __restrict__ dil_b,
        const float* __restrict__ one_w,
        const float* __restrict__ one_b,
        float* __restrict__ l2c)
{
    const int i   = blockIdx.x;
    const int b   = blockIdx.y;
    const int own = g_l2cols[i];
    const int a0  = own - 4;
    const int tid = threadIdx.x;
    const int g   = tid >> 4;
    const int s   = tid & 15;
    const int ch  = 4 * g + (s & 3);

    __shared__ float A[9][CCH];            // setup
    __shared__ float B[8][CCH];            // L1 dst {1,4,7}
    __shared__ float cat[9][2 * CCH];      // 9.2 KB
    __shared__ float ybuf[3][CCH];

    // ---- fill concat for 9 cols ----
    const float* xb = x + b * 4 * TLEN;
    for (int v = tid; v < 9 * 256; v += 512) {
        int p   = v >> 8;
        int chv = v & 255;
        int ab  = a0 + p;
        float val = 0.f;
        if (ab < 128) {
            int t = (TLEN - 128) + ab;
            if (chv < CCH) {
                int idx = (int)xb[t];            // atom id (exact int in f32)
                val = embed_w[idx * CCH + chv];
            } else {
                int cc = chv - CCH;
                val = posamp_w[2 * cc] * xb[TLEN + t]
                    + posamp_w[2 * cc + 1] * xb[2 * TLEN + t] + posamp_b[cc];
            }
        }
        cat[p][chv] = val;
    }
    // setup weights: rows 4g..4g+3, chunks {s, s+16, s+32, s+48}
    float4 RW[16];
    const float4* rw = (const float4*)reduce_w + (size_t)(4 * g) * 64;
    #pragma unroll
    for (int r = 0; r < 4; ++r)
        #pragma unroll
        for (int j = 0; j < 4; ++j)
            RW[r * 4 + j] = rw[r * 64 + s + 16 * j];
    const float rb = reduce_b[ch];
    __syncthreads();

    // ---- setup reduce: A[t] for t in [0,9) ----
    #pragma unroll 3
    for (int t = 0; t < 9; ++t) {
        const float* sc = cat[t];
        float4 x0 = *(const float4*)(sc + 4 * s);
        float4 x1 = *(const float4*)(sc + 4 * s + 64);
        float4 x2 = *(const float4*)(sc + 4 * s + 128);
        float4 x3 = *(const float4*)(sc + 4 * s + 192);
        float a0_ = dot4(RW[0], x0) + dot4(RW[1], x1) + dot4(RW[2], x2) + dot4(RW[3], x3);
        float a1_ = dot4(RW[4], x0) + dot4(RW[5], x1) + dot4(RW[6], x2) + dot4(RW[7], x3);
        float a2_ = dot4(RW[8], x0) + dot4(RW[9], x1) + dot4(RW[10], x2) + dot4(RW[11], x3);
        float a3_ = dot4(RW[12], x0) + dot4(RW[13], x1) + dot4(RW[14], x2) + dot4(RW[15], x3);
        float tot = red16x4(a0_, a1_, a2_, a3_, s);
        if (s < 4) A[t][ch] = (a0 + t < 128) ? tot + rb : 0.f;
    }

    // ---- L1 (d=1): A -> B, dst {1,4,7} ----
    conv4<3>(A, B, nullptr,
             PK3(0,3,6), PK3(1,4,7), PK3(2,5,8), PK3(1,4,7), a0,
             dil_w, dil_b, one_w, one_b, ybuf, g, s);
    // ---- L2 (d=3): B -> global l2c[b][i] (own col < 128 by construction) ----
    conv4<1>(B, B, l2c + (size_t)(b * 28 + i) * CCH,
             PK1(1), PK1(4), PK1(7), PK1(4), a0,
             dil_w + (size_t)1 * CCH * CCH * 3, dil_b + CCH,
             one_w + (size_t)1 * CCH * CCH, one_b + CCH, ybuf, g, s);
}

// ---------------------------------------------------------------------------
// K2: per-batch tail. 8 blocks. Stage 28 L2 cols -> L3 (d=9, 10 cols, two
// conv4<5>) -> L4 (d=27) {45,46,126,127} -> L5 (d=81) {126,127} -> L6 (d=1)
// {127} -> MLP hidden layers -> h2a (ws) + pa head (out).
// E idx: sorted g_l2cols position, Z=28. D idx: L3 cols
// 0:18 1:19 2:45 3:46 4:72 5:73 6:99 7:100 8:126 9:127, Z=10.
// ---------------------------------------------------------------------------
__global__ void __launch_bounds__(512, 2) k_tail(
        const float* __restrict__ l2c,
        const float* __restrict__ dil_w,
        const float* __restrict__ dil_b,
        const float* __restrict__ one_w,
        const float* __restrict__ one_b,
        const float* __restrict__ aw1, const float* __restrict__ ab1,
        const float* __restrict__ aw2, const float* __restrict__ ab2,
        const float* __restrict__ pw1, const float* __restrict__ pb1,
        const float* __restrict__ pw2, const float* __restrict__ pb2,
        const float* __restrict__ pw3, const float* __restrict__ pb3,
        float* __restrict__ h2w,
        float* __restrict__ out)
{
    const int b   = blockIdx.x;
    const int tid = threadIdx.x;
    const int g   = tid >> 4;
    const int s   = tid & 15;

    __shared__ float E[29][CCH];           // 28 L2 cols + Z
    __shared__ float D[11][CCH];           // 10 L3 cols + Z
    __shared__ float B2[5][CCH];           // L4 {45,46,126,127} + Z
    __shared__ float C2[3][CCH];           // L5 {126,127} + Z
    __shared__ float HF[CCH];              // L6 {127}
    __shared__ float ybuf[5][CCH];
    __shared__ float h1a[CCH], h1p[CCH], h2p[CCH];

    if (tid < CCH) { E[28][tid] = 0.f; D[10][tid] = 0.f; B2[4][tid] = 0.f; C2[2][tid] = 0.f; }
    for (int v = tid; v < 28 * 32; v += 512) {
        int col = v >> 5, f4i = v & 31;
        *(float4*)&E[col][f4i * 4] =
            *(const float4*)(l2c + (size_t)(b * 28 + col) * CCH + f4i * 4);
    }

    const float* Wd3 = dil_w + (size_t)2 * CCH * CCH * 3;   // layer 3 (d=9)
    const float* bd3 = dil_b + 2 * CCH;
    const float* Wo3 = one_w + (size_t)2 * CCH * CCH;
    const float* bo3 = one_b + 2 * CCH;
    // L3a: D{0..4} = owns {18,19,45,46,72}
    conv4<5>(E, D, nullptr,
             PK5(0,1,6,7,12), PK5(2,3,8,9,14), PK5(4,5,10,11,16),
             PK5(0,1,2,3,4), -1000, Wd3, bd3, Wo3, bo3, ybuf, g, s);
    // L3b: D{5..9} = owns {73,99,100,126,127} (126/127 +9 tap -> Z)
    conv4<5>(E, D, nullptr,
             PK5(13,18,19,24,25), PK5(15,20,21,26,27), PK5(17,22,23,28,28),
             PK5(5,6,7,8,9), -1000, Wd3, bd3, Wo3, bo3, ybuf, g, s);

    // L4: 45:{18,45,72} 46:{19,46,73} 126:{99,126,Z} 127:{100,127,Z}
    conv4<4>(D, B2, nullptr,
             PK4(0,1,6,7), PK4(2,3,8,9), PK4(4,5,10,10), PK4(0,1,2,3), -1000,
             dil_w + (size_t)3 * CCH * CCH * 3, dil_b + 3 * CCH,
             one_w + (size_t)3 * CCH * CCH, one_b + 3 * CCH, ybuf, g, s);
    // L5: 126:{45,126,Z} 127:{46,127,Z}
    conv4<2>(B2, C2, nullptr,
             PK2(0,1), PK2(2,3), PK2(4,4), PK2(0,1), -1000,
             dil_w + (size_t)4 * CCH * CCH * 3, dil_b + 4 * CCH,
             one_w + (size_t)4 * CCH * CCH, one_b + 4 * CCH, ybuf, g, s);
    // L6: 127:{126,127,Z} -> HF
    conv4<1>(C2, C2, HF,
             PK1(0), PK1(1), PK1(2), PK1(0), -1000,
             dil_w + (size_t)5 * CCH * CCH * 3, dil_b + 5 * CCH,
             one_w + (size_t)5 * CCH * CCH, one_b + 5 * CCH, ybuf, g, s);

    // ---- MLP hidden layers ----
    mlp4(HF, h1a, aw1, ab1, g, s);
    mlp4(HF, h1p, pw1, pb1, g, s);
    mlp4(h1a, h2w + b * CCH, aw2, ab2, g, s);   // atom h2 -> global ws
    mlp4(h1p, h2p, pw2, pb2, g, s);
    __syncthreads();

    // ---- pa head: 2 outputs, K=128 over 64 lanes ----
    if (tid < 64) {
        int row = tid >> 5, q = tid & 31;
        float4 w4 = *(const float4*)(pw3 + row * CCH + 4 * q);
        float4 xv = *(const float4*)(h2p + 4 * q);
        float acc = dot4(w4, xv);
        acc += __shfl_xor(acc, 1);
        acc += __shfl_xor(acc, 2);
        acc += __shfl_xor(acc, 4);
        acc += __shfl_xor(acc, 8);
        acc += __shfl_xor(acc, 16);
        if (q == 0) out[NBATCH * NATOMS + b * 2 + row] = acc + pb3[row];
    }
}

// ---------------------------------------------------------------------------
// K3: atom logits. grid (7, 8) x 512; block does rows [jx*512, jx*512+512).
// ---------------------------------------------------------------------------
__global__ void __launch_bounds__(512) k_head(
        const float* __restrict__ h2w,
        const float* __restrict__ aw3, const float* __restrict__ ab3,
        float* __restrict__ out)
{
    const int b   = blockIdx.y;
    const int row = blockIdx.x * 512 + threadIdx.x;
    __shared__ float hs[CCH];
    if (threadIdx.x < 32)
        *(float4*)&hs[threadIdx.x * 4] =
            *(const float4*)(h2w + b * CCH + threadIdx.x * 4);
    __syncthreads();

    const float4* r = (const float4*)(aw3 + (size_t)row * CCH);
    float s0 = 0.f, s1 = 0.f, s2 = 0.f, s3 = 0.f;
    #pragma unroll
    for (int k = 0; k < 32; k += 4) {
        s0 += dot4(r[k],     *(const float4*)&hs[4 * k]);
        s1 += dot4(r[k + 1], *(const float4*)&hs[4 * k + 4]);
        s2 += dot4(r[k + 2], *(const float4*)&hs[4 * k + 8]);
        s3 += dot4(r[k + 3], *(const float4*)&hs[4 * k + 12]);
    }
    out[b * NATOMS + row] = s0 + s1 + s2 + s3 + ab3[row];
}

// ---------------------------------------------------------------------------
extern "C" void kernel_launch(void* const* d_in, const int* in_sizes, int n_in,
                              void* d_out, int out_size, void* d_ws, size_t ws_size,
                              hipStream_t stream)
{
    const float* x        = (const float*)d_in[0];
    const float* embed_w  = (const float*)d_in[1];
    const float* posamp_w = (const float*)d_in[2];
    const float* posamp_b = (const float*)d_in[3];
    const float* reduce_w = (const float*)d_in[4];
    const float* reduce_b = (const float*)d_in[5];
    const float* dil_w    = (const float*)d_in[6];
    const float* dil_b    = (const float*)d_in[7];
    const float* one_w    = (const float*)d_in[8];
    const float* one_b    = (const float*)d_in[9];
    const float* aw1 = (const float*)d_in[10]; const float* ab1 = (const float*)d_in[11];
    const float* aw2 = (const float*)d_in[12]; const float* ab2 = (const float*)d_in[13];
    const float* aw3 = (const float*)d_in[14]; const float* ab3 = (const float*)d_in[15];
    const float* pw1 = (const float*)d_in[16]; const float* pb1 = (const float*)d_in[17];
    const float* pw2 = (const float*)d_in[18]; const float* pb2 = (const float*)d_in[19];
    const float* pw3 = (const float*)d_in[20]; const float* pb3 = (const float*)d_in[21];

    float* l2c = (float*)d_ws;                 // [8][28][128] = 114 KB
    float* h2w = l2c + NBATCH * 28 * CCH;      // [8][128]

    k_cone<<<dim3(28, NBATCH), dim3(512), 0, stream>>>(
        x, embed_w, posamp_w, posamp_b, reduce_w, reduce_b,
        dil_w, dil_b, one_w, one_b, l2c);

    k_tail<<<dim3(NBATCH), dim3(512), 0, stream>>>(
        l2c, dil_w, dil_b, one_w, one_b,
        aw1, ab1, aw2, ab2, pw1, pb1, pw2, pb2, pw3, pb3,
        h2w, (float*)d_out);

    k_head<<<dim3(7, NBATCH), dim3(512), 0, stream>>>(
        h2w, aw3, ab3, (float*)d_out);
}

// Round 9
// 55.216 us; speedup vs baseline: 5.2186x; 1.1228x over previous
//
#include <hip/hip_runtime.h>

#define CCH 128      // channels
#define TLEN 2048
#define NBATCH 8
#define NATOMS 3584
#define NEG 0.2f
typedef unsigned long long ull;

// 7-bit packed index lists (up to 9 slots in 63 bits)
#define PK1(a) ((ull)(a))
#define PK2(a,b) (PK1(a)|((ull)(b)<<7))
#define PK3(a,b,c) (PK2(a,b)|((ull)(c)<<14))
#define PK4(a,b,c,d) (PK3(a,b,c)|((ull)(d)<<21))
#define PK5(a,b,c,d,e) (PK4(a,b,c,d)|((ull)(e)<<28))

// Per-batch unique L2 columns (union of {o-9,o,o+9} for L3 cols
// o in {18,19,45,46,72,73,99,100,126,127}), sorted:
__device__ const int g_l2cols[28] = {
    9,10,18,19,27,28,36,37,45,46,54,55,63,64,
    72,73,81,82,90,91,99,100,108,109,117,118,126,127};

__device__ __forceinline__ float lrelu(float v) { return v >= 0.f ? v : NEG * v; }
__device__ __forceinline__ float dot4(float4 w, float4 x) {
    return w.x * x.x + w.y * x.y + w.z * x.z + w.w * x.w;
}

// Touch weights to warm L2/Infinity-Cache (keep-alive defeats DCE, rule #17).
__device__ __forceinline__ void warm(const float* p, int nf4, int gid, int nthr) {
    const float4* q = (const float4*)p;
    for (int i = gid; i < nf4; i += nthr) {
        float4 v = q[i];
        asm volatile("" :: "v"(v.x), "v"(v.y), "v"(v.z), "v"(v.w));
    }
}

// Reduce 4 accumulators over the 16 K-split lanes (tid = g*16+s).
// Returns the full sum of acc_{s&3}; lane s holds out-ch 4g + (s&3).
__device__ __forceinline__ float red16x4(float a0, float a1, float a2, float a3, int s) {
    a0 += __shfl_xor(a0, 8); a1 += __shfl_xor(a1, 8);
    a2 += __shfl_xor(a2, 8); a3 += __shfl_xor(a3, 8);
    a0 += __shfl_xor(a0, 4); a1 += __shfl_xor(a1, 4);
    a2 += __shfl_xor(a2, 4); a3 += __shfl_xor(a3, 4);
    float u0 = (s & 2) ? a2 : a0;
    float v0 = (s & 2) ? a0 : a2;
    u0 += __shfl_xor(v0, 2);
    float u1 = (s & 2) ? a3 : a1;
    float v1 = (s & 2) ? a1 : a3;
    u1 += __shfl_xor(v1, 2);
    float w  = (s & 1) ? u1 : u0;
    float vv = (s & 1) ? u0 : u1;
    w += __shfl_xor(vv, 1);
    return w;
}

// One residual dilated block over NB (compile-time) scratch columns.
// R=4 out-ch/thread (rows 4g..4g+3), S=16 K-split: lane s owns in-ch chunks
// {4s..4s+3, 64+4s..64+4s+3} (strided -> conflict-free LDS banks).
// pm/pc/pp/pd: packed src(-d), src(0)=residual, src(+d), dst columns.
// dst col forced 0 when a0+jd >= 128; gout!=null (NB==1): write gout[ch].
template<int NB>
__device__ __forceinline__ void conv4(
        const float (*src)[CCH], float (*dst)[CCH], float* gout,
        ull pm, ull pc, ull pp, ull pd, int a0,
        const float* __restrict__ Wd, const float* __restrict__ bd,
        const float* __restrict__ Wo, const float* __restrict__ bo,
        float (*ybuf)[CCH], int g, int s)
{
    const int ch = 4 * g + (s & 3);
    const float myBd = bd[ch];
    const float myBo = bo[ch];
    float4 W[24], V[8];
    {
        const float4* Wr = (const float4*)Wd + (size_t)(4 * g) * 96;
        #pragma unroll
        for (int r = 0; r < 4; ++r)
            #pragma unroll
            for (int j = 0; j < 3; ++j) {
                W[r * 6 + j]     = Wr[r * 96 + 3 * s + j];
                W[r * 6 + 3 + j] = Wr[r * 96 + 3 * s + 48 + j];
            }
        const float4* Or = (const float4*)Wo + (size_t)(4 * g) * 32;
        #pragma unroll
        for (int r = 0; r < 4; ++r) {
            V[r * 2]     = Or[r * 32 + s];
            V[r * 2 + 1] = Or[r * 32 + s + 16];
        }
    }
    __syncthreads();                     // src ready + ybuf free
    #pragma unroll
    for (int t = 0; t < NB; ++t) {
        const float* fm = src[(int)((pm >> (7 * t)) & 127)];
        const float* fc = src[(int)((pc >> (7 * t)) & 127)];
        const float* fp = src[(int)((pp >> (7 * t)) & 127)];
        float4 m0 = *(const float4*)(fm + 4 * s);
        float4 m1 = *(const float4*)(fm + 4 * s + 64);
        float4 c0 = *(const float4*)(fc + 4 * s);
        float4 c1 = *(const float4*)(fc + 4 * s + 64);
        float4 p0 = *(const float4*)(fp + 4 * s);
        float4 p1 = *(const float4*)(fp + 4 * s + 64);
        float acc[4];
        #pragma unroll
        for (int r = 0; r < 4; ++r) {
            float4 wA = W[r*6+0], wB = W[r*6+1], wC = W[r*6+2];
            float a = wA.x*m0.x + wA.y*c0.x + wA.z*p0.x + wA.w*m0.y
                    + wB.x*c0.y + wB.y*p0.y + wB.z*m0.z + wB.w*c0.z
                    + wC.x*p0.z + wC.y*m0.w + wC.z*c0.w + wC.w*p0.w;
            float4 wD = W[r*6+3], wE = W[r*6+4], wF = W[r*6+5];
            float b2 = wD.x*m1.x + wD.y*c1.x + wD.z*p1.x + wD.w*m1.y
                     + wE.x*c1.y + wE.y*p1.y + wE.z*m1.z + wE.w*c1.z
                     + wF.x*p1.z + wF.y*m1.w + wF.z*c1.w + wF.w*p1.w;
            acc[r] = a + b2;
        }
        float tot = red16x4(acc[0], acc[1], acc[2], acc[3], s);
        if (s < 4) ybuf[t][ch] = tot + myBd;
    }
    __syncthreads();                     // ybuf ready
    #pragma unroll
    for (int t = 0; t < NB; ++t) {
        int jc = (int)((pc >> (7 * t)) & 127);
        int jd = (int)((pd >> (7 * t)) & 127);
        const float* y = ybuf[t];
        float4 y0 = *(const float4*)(y + 4 * s);
        float4 y1 = *(const float4*)(y + 4 * s + 64);
        float a0_ = dot4(V[0], y0) + dot4(V[1], y1);
        float a1_ = dot4(V[2], y0) + dot4(V[3], y1);
        float a2_ = dot4(V[4], y0) + dot4(V[5], y1);
        float a3_ = dot4(V[6], y0) + dot4(V[7], y1);
        float tot = red16x4(a0_, a1_, a2_, a3_, s);
        if (s < 4) {
            float h = lrelu(tot + myBo + src[jc][ch]);
            if (gout) gout[ch] = h;
            else      dst[jd][ch] = (a0 + jd < 128) ? h : 0.f;
        }
    }
}

// K=128 matvec stage (MLP hidden layer), same R=4/S=16 mapping, lrelu.
__device__ __forceinline__ void mlp4(
        const float* hin, float* hout,
        const float* __restrict__ w, const float* __restrict__ bv,
        int g, int s)
{
    const int ch = 4 * g + (s & 3);
    const float myB = bv[ch];
    float4 V[8];
    const float4* r = (const float4*)w + (size_t)(4 * g) * 32;
    #pragma unroll
    for (int rr = 0; rr < 4; ++rr) {
        V[rr * 2]     = r[rr * 32 + s];
        V[rr * 2 + 1] = r[rr * 32 + s + 16];
    }
    __syncthreads();                     // hin ready
    float4 x0 = *(const float4*)(hin + 4 * s);
    float4 x1 = *(const float4*)(hin + 4 * s + 64);
    float a0_ = dot4(V[0], x0) + dot4(V[1], x1);
    float a1_ = dot4(V[2], x0) + dot4(V[3], x1);
    float a2_ = dot4(V[4], x0) + dot4(V[5], x1);
    float a3_ = dot4(V[6], x0) + dot4(V[7], x1);
    float tot = red16x4(a0_, a1_, a2_, a3_, s);
    if (s < 4) hout[ch] = lrelu(tot + myB);
}

// ---------------------------------------------------------------------------
// K1: mini-cone for one L2 column. grid (28, 8): i = blockIdx.x (L2-col idx),
// b = blockIdx.y. own = g_l2cols[i]; scratch j: abs = a0 + j, a0 = own-4.
// setup j in [0,9); L1 (d=1) dst {1,4,7}; L2 (d=3) dst {4} -> l2c[b][i][:].
// Exact: left reach abs >= 5 (own >= 9); right cols >= 128 zero-masked.
// Also warms L3 cache with all downstream weights (the harness's 268 MB
// ws-poison fill flushes Infinity Cache between replays).
// ---------------------------------------------------------------------------
__global__ void __launch_bounds__(512, 2) k_cone(
        const float* __restrict__ x,
        const float* __restrict__ embed_w,
        const float* __restrict__ posamp_w,
        const float* __restrict__ posamp_b,
        const float* __restrict__ reduce_w,
        const float* __restrict__ reduce_b,
        const float* __restrict__ dil_w,
        const float* __restrict__ dil_b,
        const float* __restrict__ one_w,
        const float* __restrict__ one_b,
        const float* __restrict__ aw1, const float* __restrict__ aw2,
        const float* __restrict__ pw1, const float* __restrict__ pw2,
        const float* __restrict__ aw3,
        float* __restrict__ l2c)
{
    const int i   = blockIdx.x;
    const int b   = blockIdx.y;
    const int own = g_l2cols[i];
    const int a0  = own - 4;
    const int tid = threadIdx.x;
    const int g   = tid >> 4;
    const int s   = tid & 15;
    const int ch  = 4 * g + (s & 3);

    // ---- prefetch downstream weights into L3 (parallel across 224 blocks) ----
    {
        const int gid  = (b * 28 + i) * 512 + tid;
        const int nthr = 224 * 512;
        warm(dil_w + (size_t)2 * CCH * CCH * 3, 4 * CCH * CCH * 3 / 4, gid, nthr);
        warm(one_w + (size_t)2 * CCH * CCH,     4 * CCH * CCH / 4,     gid, nthr);
        warm(aw1, CCH * CCH / 4, gid, nthr);
        warm(aw2, CCH * CCH / 4, gid, nthr);
        warm(pw1, CCH * CCH / 4, gid, nthr);
        warm(pw2, CCH * CCH / 4, gid, nthr);
        warm(aw3, NATOMS * CCH / 4, gid, nthr);
    }

    __shared__ float A[9][CCH];            // setup
    __shared__ float B[8][CCH];            // L1 dst {1,4,7}
    __shared__ float cat[9][2 * CCH];      // 9.2 KB
    __shared__ float ybuf[3][CCH];

    // ---- fill concat for 9 cols ----
    const float* xb = x + b * 4 * TLEN;
    for (int v = tid; v < 9 * 256; v += 512) {
        int p   = v >> 8;
        int chv = v & 255;
        int ab  = a0 + p;
        float val = 0.f;
        if (ab < 128) {
            int t = (TLEN - 128) + ab;
            if (chv < CCH) {
                int idx = (int)xb[t];            // atom id (exact int in f32)
                val = embed_w[idx * CCH + chv];
            } else {
                int cc = chv - CCH;
                val = posamp_w[2 * cc] * xb[TLEN + t]
                    + posamp_w[2 * cc + 1] * xb[2 * TLEN + t] + posamp_b[cc];
            }
        }
        cat[p][chv] = val;
    }
    // setup weights: rows 4g..4g+3, chunks {s, s+16, s+32, s+48}
    float4 RW[16];
    const float4* rw = (const float4*)reduce_w + (size_t)(4 * g) * 64;
    #pragma unroll
    for (int r = 0; r < 4; ++r)
        #pragma unroll
        for (int j = 0; j < 4; ++j)
            RW[r * 4 + j] = rw[r * 64 + s + 16 * j];
    const float rb = reduce_b[ch];
    __syncthreads();

    // ---- setup reduce: A[t] for t in [0,9) ----
    #pragma unroll 3
    for (int t = 0; t < 9; ++t) {
        const float* sc = cat[t];
        float4 x0 = *(const float4*)(sc + 4 * s);
        float4 x1 = *(const float4*)(sc + 4 * s + 64);
        float4 x2 = *(const float4*)(sc + 4 * s + 128);
        float4 x3 = *(const float4*)(sc + 4 * s + 192);
        float a0_ = dot4(RW[0], x0) + dot4(RW[1], x1) + dot4(RW[2], x2) + dot4(RW[3], x3);
        float a1_ = dot4(RW[4], x0) + dot4(RW[5], x1) + dot4(RW[6], x2) + dot4(RW[7], x3);
        float a2_ = dot4(RW[8], x0) + dot4(RW[9], x1) + dot4(RW[10], x2) + dot4(RW[11], x3);
        float a3_ = dot4(RW[12], x0) + dot4(RW[13], x1) + dot4(RW[14], x2) + dot4(RW[15], x3);
        float tot = red16x4(a0_, a1_, a2_, a3_, s);
        if (s < 4) A[t][ch] = (a0 + t < 128) ? tot + rb : 0.f;
    }

    // ---- L1 (d=1): A -> B, dst {1,4,7} ----
    conv4<3>(A, B, nullptr,
             PK3(0,3,6), PK3(1,4,7), PK3(2,5,8), PK3(1,4,7), a0,
             dil_w, dil_b, one_w, one_b, ybuf, g, s);
    // ---- L2 (d=3): B -> global l2c[b][i] (own col < 128 by construction) ----
    conv4<1>(B, B, l2c + (size_t)(b * 28 + i) * CCH,
             PK1(1), PK1(4), PK1(7), PK1(4), a0,
             dil_w + (size_t)1 * CCH * CCH * 3, dil_b + CCH,
             one_w + (size_t)1 * CCH * CCH, one_b + CCH, ybuf, g, s);
}

// ---------------------------------------------------------------------------
// K2: L3 (d=9) for one (L3-col, batch). grid (10, 8) = 80 blocks.
// L3 col i owns o = {18,19,45,46,72,73,99,100,126,127}[i]; taps o-9,o,o+9
// map to l2c indices jm = 6*(i>>1)+(i&1), jc = jm+2, jp = jm+4 (Z for i>=8).
// ---------------------------------------------------------------------------
__global__ void __launch_bounds__(512, 2) k_l3(
        const float* __restrict__ l2c,
        const float* __restrict__ dil_w,
        const float* __restrict__ dil_b,
        const float* __restrict__ one_w,
        const float* __restrict__ one_b,
        float* __restrict__ d3c)
{
    const int i   = blockIdx.x;
    const int b   = blockIdx.y;
    const int tid = threadIdx.x;
    const int g   = tid >> 4;
    const int s   = tid & 15;

    __shared__ float E3[4][CCH];           // taps -9, 0, +9, Z
    __shared__ float ybuf[1][CCH];

    const int jm = 6 * (i >> 1) + (i & 1);
    const bool hasp = (i < 8);
    if (tid < CCH) E3[3][tid] = 0.f;
    if (tid < 384) {
        int col = tid >> 7, f4i = tid & 31;          // col 0..2, f4i 0..31
        int src = (col == 0) ? jm : (col == 1) ? jm + 2 : (hasp ? jm + 4 : -1);
        float4 v = make_float4(0.f, 0.f, 0.f, 0.f);
        if (src >= 0)
            v = *(const float4*)(l2c + (size_t)(b * 28 + src) * CCH + f4i * 4);
        *(float4*)&E3[col][f4i * 4] = v;
    }

    conv4<1>(E3, E3, d3c + (size_t)(b * 10 + i) * CCH,
             PK1(0), PK1(1), PK1(2), PK1(0), -1000,
             dil_w + (size_t)2 * CCH * CCH * 3, dil_b + 2 * CCH,
             one_w + (size_t)2 * CCH * CCH, one_b + 2 * CCH, ybuf, g, s);
}

// ---------------------------------------------------------------------------
// K3: per-batch tail. 8 blocks. Stage 10 L3 cols -> L4 (d=27) {45,46,126,127}
// -> L5 (d=81) {126,127} -> L6 (d=1) {127} -> MLP hidden layers -> h2a (ws)
// + pa head (out). D idx: 0:18 1:19 2:45 3:46 4:72 5:73 6:99 7:100 8:126
// 9:127, Z=10.
// ---------------------------------------------------------------------------
__global__ void __launch_bounds__(512, 2) k_tail(
        const float* __restrict__ d3c,
        const float* __restrict__ dil_w,
        const float* __restrict__ dil_b,
        const float* __restrict__ one_w,
        const float* __restrict__ one_b,
        const float* __restrict__ aw1, const float* __restrict__ ab1,
        const float* __restrict__ aw2, const float* __restrict__ ab2,
        const float* __restrict__ pw1, const float* __restrict__ pb1,
        const float* __restrict__ pw2, const float* __restrict__ pb2,
        const float* __restrict__ pw3, const float* __restrict__ pb3,
        float* __restrict__ h2w,
        float* __restrict__ out)
{
    const int b   = blockIdx.x;
    const int tid = threadIdx.x;
    const int g   = tid >> 4;
    const int s   = tid & 15;

    __shared__ float D[11][CCH];           // 10 L3 cols + Z
    __shared__ float B2[5][CCH];           // L4 {45,46,126,127} + Z
    __shared__ float C2[3][CCH];           // L5 {126,127} + Z
    __shared__ float HF[CCH];              // L6 {127}
    __shared__ float ybuf[4][CCH];
    __shared__ float h1a[CCH], h1p[CCH], h2p[CCH];

    if (tid < CCH) { D[10][tid] = 0.f; B2[4][tid] = 0.f; C2[2][tid] = 0.f; }
    if (tid < 320) {
        int col = tid >> 5, f4i = tid & 31;
        *(float4*)&D[col][f4i * 4] =
            *(const float4*)(d3c + (size_t)(b * 10 + col) * CCH + f4i * 4);
    }

    // L4: 45:{18,45,72} 46:{19,46,73} 126:{99,126,Z} 127:{100,127,Z}
    conv4<4>(D, B2, nullptr,
             PK4(0,1,6,7), PK4(2,3,8,9), PK4(4,5,10,10), PK4(0,1,2,3), -1000,
             dil_w + (size_t)3 * CCH * CCH * 3, dil_b + 3 * CCH,
             one_w + (size_t)3 * CCH * CCH, one_b + 3 * CCH, ybuf, g, s);
    // L5: 126:{45,126,Z} 127:{46,127,Z}
    conv4<2>(B2, C2, nullptr,
             PK2(0,1), PK2(2,3), PK2(4,4), PK2(0,1), -1000,
             dil_w + (size_t)4 * CCH * CCH * 3, dil_b + 4 * CCH,
             one_w + (size_t)4 * CCH * CCH, one_b + 4 * CCH, ybuf, g, s);
    // L6: 127:{126,127,Z} -> HF
    conv4<1>(C2, C2, HF,
             PK1(0), PK1(1), PK1(2), PK1(0), -1000,
             dil_w + (size_t)5 * CCH * CCH * 3, dil_b + 5 * CCH,
             one_w + (size_t)5 * CCH * CCH, one_b + 5 * CCH, ybuf, g, s);

    // ---- MLP hidden layers ----
    mlp4(HF, h1a, aw1, ab1, g, s);
    mlp4(HF, h1p, pw1, pb1, g, s);
    mlp4(h1a, h2w + b * CCH, aw2, ab2, g, s);   // atom h2 -> global ws
    mlp4(h1p, h2p, pw2, pb2, g, s);
    __syncthreads();

    // ---- pa head: 2 outputs, K=128 over 64 lanes ----
    if (tid < 64) {
        int row = tid >> 5, q = tid & 31;
        float4 w4 = *(const float4*)(pw3 + row * CCH + 4 * q);
        float4 xv = *(const float4*)(h2p + 4 * q);
        float acc = dot4(w4, xv);
        acc += __shfl_xor(acc, 1);
        acc += __shfl_xor(acc, 2);
        acc += __shfl_xor(acc, 4);
        acc += __shfl_xor(acc, 8);
        acc += __shfl_xor(acc, 16);
        if (q == 0) out[NBATCH * NATOMS + b * 2 + row] = acc + pb3[row];
    }
}

// ---------------------------------------------------------------------------
// K4: atom logits. grid (7, 8) x 512; block does rows [jx*512, jx*512+512).
// ---------------------------------------------------------------------------
__global__ void __launch_bounds__(512) k_head(
        const float* __restrict__ h2w,
        const float* __restrict__ aw3, const float* __restrict__ ab3,
        float* __restrict__ out)
{
    const int b   = blockIdx.y;
    const int row = blockIdx.x * 512 + threadIdx.x;
    __shared__ float hs[CCH];
    if (threadIdx.x < 32)
        *(float4*)&hs[threadIdx.x * 4] =
            *(const float4*)(h2w + b * CCH + threadIdx.x * 4);
    __syncthreads();

    const float4* r = (const float4*)(aw3 + (size_t)row * CCH);
    float s0 = 0.f, s1 = 0.f, s2 = 0.f, s3 = 0.f;
    #pragma unroll
    for (int k = 0; k < 32; k += 4) {
        s0 += dot4(r[k],     *(const float4*)&hs[4 * k]);
        s1 += dot4(r[k + 1], *(const float4*)&hs[4 * k + 4]);
        s2 += dot4(r[k + 2], *(const float4*)&hs[4 * k + 8]);
        s3 += dot4(r[k + 3], *(const float4*)&hs[4 * k + 12]);
    }
    out[b * NATOMS + row] = s0 + s1 + s2 + s3 + ab3[row];
}

// ---------------------------------------------------------------------------
extern "C" void kernel_launch(void* const* d_in, const int* in_sizes, int n_in,
                              void* d_out, int out_size, void* d_ws, size_t ws_size,
                              hipStream_t stream)
{
    const float* x        = (const float*)d_in[0];
    const float* embed_w  = (const float*)d_in[1];
    const float* posamp_w = (const float*)d_in[2];
    const float* posamp_b = (const float*)d_in[3];
    const float* reduce_w = (const float*)d_in[4];
    const float* reduce_b = (const float*)d_in[5];
    const float* dil_w    = (const float*)d_in[6];
    const float* dil_b    = (const float*)d_in[7];
    const float* one_w    = (const float*)d_in[8];
    const float* one_b    = (const float*)d_in[9];
    const float* aw1 = (const float*)d_in[10]; const float* ab1 = (const float*)d_in[11];
    const float* aw2 = (const float*)d_in[12]; const float* ab2 = (const float*)d_in[13];
    const float* aw3 = (const float*)d_in[14]; const float* ab3 = (const float*)d_in[15];
    const float* pw1 = (const float*)d_in[16]; const float* pb1 = (const float*)d_in[17];
    const float* pw2 = (const float*)d_in[18]; const float* pb2 = (const float*)d_in[19];
    const float* pw3 = (const float*)d_in[20]; const float* pb3 = (const float*)d_in[21];

    float* l2c = (float*)d_ws;                 // [8][28][128] = 114 KB
    float* d3c = l2c + NBATCH * 28 * CCH;      // [8][10][128]
    float* h2w = d3c + NBATCH * 10 * CCH;      // [8][128]

    k_cone<<<dim3(28, NBATCH), dim3(512), 0, stream>>>(
        x, embed_w, posamp_w, posamp_b, reduce_w, reduce_b,
        dil_w, dil_b, one_w, one_b,
        aw1, aw2, pw1, pw2, aw3, l2c);

    k_l3<<<dim3(10, NBATCH), dim3(512), 0, stream>>>(
        l2c, dil_w, dil_b, one_w, one_b, d3c);

    k_tail<<<dim3(NBATCH), dim3(512), 0, stream>>>(
        d3c, dil_w, dil_b, one_w, one_b,
        aw1, ab1, aw2, ab2, pw1, pb1, pw2, pb2, pw3, pb3,
        h2w, (float*)d_out);

    k_head<<<dim3(7, NBATCH), dim3(512), 0, stream>>>(
        h2w, aw3, ab3, (float*)d_out);
}

// Round 10
// 52.467 us; speedup vs baseline: 5.4921x; 1.0524x over previous
//
#include <hip/hip_runtime.h>

#define CCH 128      // channels
#define TLEN 2048
#define NBATCH 8
#define NATOMS 3584
#define NEG 0.2f
typedef unsigned long long ull;

// 7-bit packed index lists (up to 9 slots)
#define PK1(a) ((ull)(a))
#define PK2(a,b) (PK1(a)|((ull)(b)<<7))
#define PK3(a,b,c) (PK2(a,b)|((ull)(c)<<14))
#define PK4(a,b,c,d) (PK3(a,b,c)|((ull)(d)<<21))
#define PK5(a,b,c,d,e) (PK4(a,b,c,d)|((ull)(e)<<28))
// 6-bit packed (10 slots in 60 bits)
#define P6(v,k) ((ull)(v)<<(6*(k)))
#define PX10(a,b,c,d,e,f,g,h,i,j) (P6(a,0)|P6(b,1)|P6(c,2)|P6(d,3)|P6(e,4)| \
    P6(f,5)|P6(g,6)|P6(h,7)|P6(i,8)|P6(j,9))

// Per-batch unique L2 columns (union of {o-9,o,o+9} for L3 cols
// o in {18,19,45,46,72,73,99,100,126,127}), sorted:
__device__ const int g_l2cols[28] = {
    9,10,18,19,27,28,36,37,45,46,54,55,63,64,
    72,73,81,82,90,91,99,100,108,109,117,118,126,127};

__device__ __forceinline__ float lrelu(float v) { return v >= 0.f ? v : NEG * v; }
__device__ __forceinline__ float dot4(float4 w, float4 x) {
    return w.x * x.x + w.y * x.y + w.z * x.z + w.w * x.w;
}

// Touch weights to warm L3 (keep-alive defeats DCE, rule #17).
__device__ __forceinline__ void warm(const float* p, int nf4, int gid, int nthr) {
    const float4* q = (const float4*)p;
    for (int i = gid; i < nf4; i += nthr) {
        float4 v = q[i];
        asm volatile("" :: "v"(v.x), "v"(v.y), "v"(v.z), "v"(v.w));
    }
}

// Reduce 4 accumulators over the 16 K-split lanes (tid = g*16+s).
// Returns the full sum of acc_{s&3}; lane s holds out-ch 4g + (s&3).
__device__ __forceinline__ float red16x4(float a0, float a1, float a2, float a3, int s) {
    a0 += __shfl_xor(a0, 8); a1 += __shfl_xor(a1, 8);
    a2 += __shfl_xor(a2, 8); a3 += __shfl_xor(a3, 8);
    a0 += __shfl_xor(a0, 4); a1 += __shfl_xor(a1, 4);
    a2 += __shfl_xor(a2, 4); a3 += __shfl_xor(a3, 4);
    float u0 = (s & 2) ? a2 : a0;
    float v0 = (s & 2) ? a0 : a2;
    u0 += __shfl_xor(v0, 2);
    float u1 = (s & 2) ? a3 : a1;
    float v1 = (s & 2) ? a1 : a3;
    u1 += __shfl_xor(v1, 2);
    float w  = (s & 1) ? u1 : u0;
    float vv = (s & 1) ? u0 : u1;
    w += __shfl_xor(vv, 1);
    return w;
}

// One residual dilated block over NB (compile-time) scratch columns.
// R=4 out-ch/thread (rows 4g..4g+3), S=16 K-split: lane s owns in-ch chunks
// {4s..4s+3, 64+4s..64+4s+3} (strided -> conflict-free LDS banks).
// pm/pc/pp/pd: packed (SH bits/slot) src(-d), src(0)=residual, src(+d), dst.
// dst col forced 0 when a0+jd >= 128; gout!=null (NB==1): write gout[ch].
template<int NB, int SH = 7>
__device__ __forceinline__ void conv4(
        const float (*src)[CCH], float (*dst)[CCH], float* gout,
        ull pm, ull pc, ull pp, ull pd, int a0,
        const float* __restrict__ Wd, const float* __restrict__ bd,
        const float* __restrict__ Wo, const float* __restrict__ bo,
        float (*ybuf)[CCH], int g, int s)
{
    const int MSK = (1 << SH) - 1;
    const int ch = 4 * g + (s & 3);
    const float myBd = bd[ch];
    const float myBo = bo[ch];
    float4 W[24], V[8];
    {
        const float4* Wr = (const float4*)Wd + (size_t)(4 * g) * 96;
        #pragma unroll
        for (int r = 0; r < 4; ++r)
            #pragma unroll
            for (int j = 0; j < 3; ++j) {
                W[r * 6 + j]     = Wr[r * 96 + 3 * s + j];
                W[r * 6 + 3 + j] = Wr[r * 96 + 3 * s + 48 + j];
            }
        const float4* Or = (const float4*)Wo + (size_t)(4 * g) * 32;
        #pragma unroll
        for (int r = 0; r < 4; ++r) {
            V[r * 2]     = Or[r * 32 + s];
            V[r * 2 + 1] = Or[r * 32 + s + 16];
        }
    }
    __syncthreads();                     // src ready + ybuf free
    #pragma unroll
    for (int t = 0; t < NB; ++t) {
        const float* fm = src[(int)((pm >> (SH * t)) & MSK)];
        const float* fc = src[(int)((pc >> (SH * t)) & MSK)];
        const float* fp = src[(int)((pp >> (SH * t)) & MSK)];
        float4 m0 = *(const float4*)(fm + 4 * s);
        float4 m1 = *(const float4*)(fm + 4 * s + 64);
        float4 c0 = *(const float4*)(fc + 4 * s);
        float4 c1 = *(const float4*)(fc + 4 * s + 64);
        float4 p0 = *(const float4*)(fp + 4 * s);
        float4 p1 = *(const float4*)(fp + 4 * s + 64);
        float acc[4];
        #pragma unroll
        for (int r = 0; r < 4; ++r) {
            float4 wA = W[r*6+0], wB = W[r*6+1], wC = W[r*6+2];
            float a = wA.x*m0.x + wA.y*c0.x + wA.z*p0.x + wA.w*m0.y
                    + wB.x*c0.y + wB.y*p0.y + wB.z*m0.z + wB.w*c0.z
                    + wC.x*p0.z + wC.y*m0.w + wC.z*c0.w + wC.w*p0.w;
            float4 wD = W[r*6+3], wE = W[r*6+4], wF = W[r*6+5];
            float b2 = wD.x*m1.x + wD.y*c1.x + wD.z*p1.x + wD.w*m1.y
                     + wE.x*c1.y + wE.y*p1.y + wE.z*m1.z + wE.w*c1.z
                     + wF.x*p1.z + wF.y*m1.w + wF.z*c1.w + wF.w*p1.w;
            acc[r] = a + b2;
        }
        float tot = red16x4(acc[0], acc[1], acc[2], acc[3], s);
        if (s < 4) ybuf[t][ch] = tot + myBd;
    }
    __syncthreads();                     // ybuf ready
    #pragma unroll
    for (int t = 0; t < NB; ++t) {
        int jc = (int)((pc >> (SH * t)) & MSK);
        int jd = (int)((pd >> (SH * t)) & MSK);
        const float* y = ybuf[t];
        float4 y0 = *(const float4*)(y + 4 * s);
        float4 y1 = *(const float4*)(y + 4 * s + 64);
        float a0_ = dot4(V[0], y0) + dot4(V[1], y1);
        float a1_ = dot4(V[2], y0) + dot4(V[3], y1);
        float a2_ = dot4(V[4], y0) + dot4(V[5], y1);
        float a3_ = dot4(V[6], y0) + dot4(V[7], y1);
        float tot = red16x4(a0_, a1_, a2_, a3_, s);
        if (s < 4) {
            float h = lrelu(tot + myBo + src[jc][ch]);
            if (gout) gout[ch] = h;
            else      dst[jd][ch] = (a0 + jd < 128) ? h : 0.f;
        }
    }
}

// K=128 matvec stage (MLP hidden layer), same R=4/S=16 mapping, lrelu.
__device__ __forceinline__ void mlp4(
        const float* hin, float* hout,
        const float* __restrict__ w, const float* __restrict__ bv,
        int g, int s)
{
    const int ch = 4 * g + (s & 3);
    const float myB = bv[ch];
    float4 V[8];
    const float4* r = (const float4*)w + (size_t)(4 * g) * 32;
    #pragma unroll
    for (int rr = 0; rr < 4; ++rr) {
        V[rr * 2]     = r[rr * 32 + s];
        V[rr * 2 + 1] = r[rr * 32 + s + 16];
    }
    __syncthreads();                     // hin ready
    float4 x0 = *(const float4*)(hin + 4 * s);
    float4 x1 = *(const float4*)(hin + 4 * s + 64);
    float a0_ = dot4(V[0], x0) + dot4(V[1], x1);
    float a1_ = dot4(V[2], x0) + dot4(V[3], x1);
    float a2_ = dot4(V[4], x0) + dot4(V[5], x1);
    float a3_ = dot4(V[6], x0) + dot4(V[7], x1);
    float tot = red16x4(a0_, a1_, a2_, a3_, s);
    if (s < 4) hout[ch] = lrelu(tot + myB);
}

// ---------------------------------------------------------------------------
// K1: mini-cone for one L2 column. grid (28, 8): i = blockIdx.x (L2-col idx),
// b = blockIdx.y. own = g_l2cols[i]; scratch j: abs = a0 + j, a0 = own-4.
// setup j in [0,9); L1 (d=1) dst {1,4,7}; L2 (d=3) dst {4} -> l2c[b][i][:].
// Exact: left reach abs >= 5 (own >= 9); right cols >= 128 zero-masked.
// Also warms L3 cache with all downstream weights (the harness's 268 MB
// ws-poison fill flushes Infinity Cache between replays).
// ---------------------------------------------------------------------------
__global__ void __launch_bounds__(512, 2) k_cone(
        const float* __restrict__ x,
        const float* __restrict__ embed_w,
        const float* __restrict__ posamp_w,
        const float* __restrict__ posamp_b,
        const float* __restrict__ reduce_w,
        const float* __restrict__ reduce_b,
        const float* __restrict__ dil_w,
        const float* __restrict__ dil_b,
        const float* __restrict__ one_w,
        const float* __restrict__ one_b,
        const float* __restrict__ aw1, const float* __restrict__ aw2,
        const float* __restrict__ pw1, const float* __restrict__ pw2,
        const float* __restrict__ aw3,
        float* __restrict__ l2c)
{
    const int i   = blockIdx.x;
    const int b   = blockIdx.y;
    const int own = g_l2cols[i];
    const int a0  = own - 4;
    const int tid = threadIdx.x;
    const int g   = tid >> 4;
    const int s   = tid & 15;
    const int ch  = 4 * g + (s & 3);

    // ---- prefetch downstream weights into L3 (parallel across 224 blocks) ----
    {
        const int gid  = (b * 28 + i) * 512 + tid;
        const int nthr = 224 * 512;
        warm(dil_w + (size_t)2 * CCH * CCH * 3, 4 * CCH * CCH * 3 / 4, gid, nthr);
        warm(one_w + (size_t)2 * CCH * CCH,     4 * CCH * CCH / 4,     gid, nthr);
        warm(aw1, CCH * CCH / 4, gid, nthr);
        warm(aw2, CCH * CCH / 4, gid, nthr);
        warm(pw1, CCH * CCH / 4, gid, nthr);
        warm(pw2, CCH * CCH / 4, gid, nthr);
        warm(aw3, NATOMS * CCH / 4, gid, nthr);
    }

    __shared__ float A[9][CCH];            // setup
    __shared__ float B[8][CCH];            // L1 dst {1,4,7}
    __shared__ float cat[9][2 * CCH];      // 9.2 KB
    __shared__ float ybuf[3][CCH];

    // ---- fill concat for 9 cols ----
    const float* xb = x + b * 4 * TLEN;
    for (int v = tid; v < 9 * 256; v += 512) {
        int p   = v >> 8;
        int chv = v & 255;
        int ab  = a0 + p;
        float val = 0.f;
        if (ab < 128) {
            int t = (TLEN - 128) + ab;
            if (chv < CCH) {
                int idx = (int)xb[t];            // atom id (exact int in f32)
                val = embed_w[idx * CCH + chv];
            } else {
                int cc = chv - CCH;
                val = posamp_w[2 * cc] * xb[TLEN + t]
                    + posamp_w[2 * cc + 1] * xb[2 * TLEN + t] + posamp_b[cc];
            }
        }
        cat[p][chv] = val;
    }
    // setup weights: rows 4g..4g+3, chunks {s, s+16, s+32, s+48}
    float4 RW[16];
    const float4* rw = (const float4*)reduce_w + (size_t)(4 * g) * 64;
    #pragma unroll
    for (int r = 0; r < 4; ++r)
        #pragma unroll
        for (int j = 0; j < 4; ++j)
            RW[r * 4 + j] = rw[r * 64 + s + 16 * j];
    const float rb = reduce_b[ch];
    __syncthreads();

    // ---- setup reduce: A[t] for t in [0,9) ----
    #pragma unroll 3
    for (int t = 0; t < 9; ++t) {
        const float* sc = cat[t];
        float4 x0 = *(const float4*)(sc + 4 * s);
        float4 x1 = *(const float4*)(sc + 4 * s + 64);
        float4 x2 = *(const float4*)(sc + 4 * s + 128);
        float4 x3 = *(const float4*)(sc + 4 * s + 192);
        float a0_ = dot4(RW[0], x0) + dot4(RW[1], x1) + dot4(RW[2], x2) + dot4(RW[3], x3);
        float a1_ = dot4(RW[4], x0) + dot4(RW[5], x1) + dot4(RW[6], x2) + dot4(RW[7], x3);
        float a2_ = dot4(RW[8], x0) + dot4(RW[9], x1) + dot4(RW[10], x2) + dot4(RW[11], x3);
        float a3_ = dot4(RW[12], x0) + dot4(RW[13], x1) + dot4(RW[14], x2) + dot4(RW[15], x3);
        float tot = red16x4(a0_, a1_, a2_, a3_, s);
        if (s < 4) A[t][ch] = (a0 + t < 128) ? tot + rb : 0.f;
    }

    // ---- L1 (d=1): A -> B, dst {1,4,7} ----
    conv4<3>(A, B, nullptr,
             PK3(0,3,6), PK3(1,4,7), PK3(2,5,8), PK3(1,4,7), a0,
             dil_w, dil_b, one_w, one_b, ybuf, g, s);
    // ---- L2 (d=3): B -> global l2c[b][i] (own col < 128 by construction) ----
    conv4<1>(B, B, l2c + (size_t)(b * 28 + i) * CCH,
             PK1(1), PK1(4), PK1(7), PK1(4), a0,
             dil_w + (size_t)1 * CCH * CCH * 3, dil_b + CCH,
             one_w + (size_t)1 * CCH * CCH, one_b + CCH, ybuf, g, s);
}

// ---------------------------------------------------------------------------
// K2: fused tail+head. grid (8, 8): g = blockIdx.x (head row-group),
// b = blockIdx.y. Each block redundantly computes (warm weights):
// stage 28 L2 cols -> L3 (d=9, conv4<10,6>) -> L4 (d=27) {45,46,126,127} ->
// L5 (d=81) {126,127} -> L6 (d=1) {127} -> MLP hidden layers (LDS) ->
// atom rows [g*448, g*448+448) (+ pa head in g==0).
// E idx: sorted g_l2cols position, Z=28. D idx: L3 cols
// 0:18 1:19 2:45 3:46 4:72 5:73 6:99 7:100 8:126 9:127, Z=10.
// ---------------------------------------------------------------------------
__global__ void __launch_bounds__(512, 2) k_tail(
        const float* __restrict__ l2c,
        const float* __restrict__ dil_w,
        const float* __restrict__ dil_b,
        const float* __restrict__ one_w,
        const float* __restrict__ one_b,
        const float* __restrict__ aw1, const float* __restrict__ ab1,
        const float* __restrict__ aw2, const float* __restrict__ ab2,
        const float* __restrict__ aw3, const float* __restrict__ ab3,
        const float* __restrict__ pw1, const float* __restrict__ pb1,
        const float* __restrict__ pw2, const float* __restrict__ pb2,
        const float* __restrict__ pw3, const float* __restrict__ pb3,
        float* __restrict__ out)
{
    const int g2  = blockIdx.x;            // head row-group
    const int b   = blockIdx.y;
    const int tid = threadIdx.x;
    const int g   = tid >> 4;
    const int s   = tid & 15;

    __shared__ float E[29][CCH];           // 28 L2 cols + Z
    __shared__ float D[11][CCH];           // 10 L3 cols + Z
    __shared__ float B2[5][CCH];           // L4 {45,46,126,127} + Z
    __shared__ float C2[3][CCH];           // L5 {126,127} + Z
    __shared__ float HF[CCH];              // L6 {127}
    __shared__ float ybuf[10][CCH];
    __shared__ float h1a[CCH], h2a[CCH], h1p[CCH], h2p[CCH];

    if (tid < CCH) { E[28][tid] = 0.f; D[10][tid] = 0.f; B2[4][tid] = 0.f; C2[2][tid] = 0.f; }
    for (int v = tid; v < 28 * 32; v += 512) {
        int col = v >> 5, f4i = v & 31;
        *(float4*)&E[col][f4i * 4] =
            *(const float4*)(l2c + (size_t)(b * 28 + col) * CCH + f4i * 4);
    }

    // L3 (d=9), all 10 cols in one weight phase (6-bit packing):
    // D t: m=E{0,1,6,7,12,13,18,19,24,25} c=E{2,3,8,9,14,15,20,21,26,27}
    //      p=E{4,5,10,11,16,17,22,23,28,28}
    conv4<10, 6>(E, D, nullptr,
             PX10(0,1,6,7,12,13,18,19,24,25),
             PX10(2,3,8,9,14,15,20,21,26,27),
             PX10(4,5,10,11,16,17,22,23,28,28),
             PX10(0,1,2,3,4,5,6,7,8,9), -1000,
             dil_w + (size_t)2 * CCH * CCH * 3, dil_b + 2 * CCH,
             one_w + (size_t)2 * CCH * CCH, one_b + 2 * CCH, ybuf, g, s);

    // L4: 45:{18,45,72} 46:{19,46,73} 126:{99,126,Z} 127:{100,127,Z}
    conv4<4>(D, B2, nullptr,
             PK4(0,1,6,7), PK4(2,3,8,9), PK4(4,5,10,10), PK4(0,1,2,3), -1000,
             dil_w + (size_t)3 * CCH * CCH * 3, dil_b + 3 * CCH,
             one_w + (size_t)3 * CCH * CCH, one_b + 3 * CCH, ybuf, g, s);
    // L5: 126:{45,126,Z} 127:{46,127,Z}
    conv4<2>(B2, C2, nullptr,
             PK2(0,1), PK2(2,3), PK2(4,4), PK2(0,1), -1000,
             dil_w + (size_t)4 * CCH * CCH * 3, dil_b + 4 * CCH,
             one_w + (size_t)4 * CCH * CCH, one_b + 4 * CCH, ybuf, g, s);
    // L6: 127:{126,127,Z} -> HF
    conv4<1>(C2, C2, HF,
             PK1(0), PK1(1), PK1(2), PK1(0), -1000,
             dil_w + (size_t)5 * CCH * CCH * 3, dil_b + 5 * CCH,
             one_w + (size_t)5 * CCH * CCH, one_b + 5 * CCH, ybuf, g, s);

    // ---- MLP hidden layers (all in LDS) ----
    mlp4(HF, h1a, aw1, ab1, g, s);
    mlp4(HF, h1p, pw1, pb1, g, s);
    mlp4(h1a, h2a, aw2, ab2, g, s);
    mlp4(h1p, h2p, pw2, pb2, g, s);
    __syncthreads();

    // ---- atom logits: rows [g2*448, g2*448+448) ----
    if (tid < 448) {
        int row = g2 * 448 + tid;
        const float4* r = (const float4*)(aw3 + (size_t)row * CCH);
        float s0 = 0.f, s1 = 0.f, s2 = 0.f, s3 = 0.f;
        #pragma unroll
        for (int k = 0; k < 32; k += 4) {
            s0 += dot4(r[k],     *(const float4*)&h2a[4 * k]);
            s1 += dot4(r[k + 1], *(const float4*)&h2a[4 * k + 4]);
            s2 += dot4(r[k + 2], *(const float4*)&h2a[4 * k + 8]);
            s3 += dot4(r[k + 3], *(const float4*)&h2a[4 * k + 12]);
        }
        out[b * NATOMS + row] = s0 + s1 + s2 + s3 + ab3[row];
    } else if (g2 == 0 && tid >= 448 && tid < 448 + 64) {
        // ---- pa head: 2 outputs, K=128 over 64 lanes ----
        int q = tid - 448;
        int row = q >> 5, qq = q & 31;
        float4 w4 = *(const float4*)(pw3 + row * CCH + 4 * qq);
        float4 xv = *(const float4*)(h2p + 4 * qq);
        float acc = dot4(w4, xv);
        acc += __shfl_xor(acc, 1);
        acc += __shfl_xor(acc, 2);
        acc += __shfl_xor(acc, 4);
        acc += __shfl_xor(acc, 8);
        acc += __shfl_xor(acc, 16);
        if (qq == 0) out[NBATCH * NATOMS + b * 2 + row] = acc + pb3[row];
    }
}

// ---------------------------------------------------------------------------
extern "C" void kernel_launch(void* const* d_in, const int* in_sizes, int n_in,
                              void* d_out, int out_size, void* d_ws, size_t ws_size,
                              hipStream_t stream)
{
    const float* x        = (const float*)d_in[0];
    const float* embed_w  = (const float*)d_in[1];
    const float* posamp_w = (const float*)d_in[2];
    const float* posamp_b = (const float*)d_in[3];
    const float* reduce_w = (const float*)d_in[4];
    const float* reduce_b = (const float*)d_in[5];
    const float* dil_w    = (const float*)d_in[6];
    const float* dil_b    = (const float*)d_in[7];
    const float* one_w    = (const float*)d_in[8];
    const float* one_b    = (const float*)d_in[9];
    const float* aw1 = (const float*)d_in[10]; const float* ab1 = (const float*)d_in[11];
    const float* aw2 = (const float*)d_in[12]; const float* ab2 = (const float*)d_in[13];
    const float* aw3 = (const float*)d_in[14]; const float* ab3 = (const float*)d_in[15];
    const float* pw1 = (const float*)d_in[16]; const float* pb1 = (const float*)d_in[17];
    const float* pw2 = (const float*)d_in[18]; const float* pb2 = (const float*)d_in[19];
    const float* pw3 = (const float*)d_in[20]; const float* pb3 = (const float*)d_in[21];

    float* l2c = (float*)d_ws;                 // [8][28][128] = 114 KB

    k_cone<<<dim3(28, NBATCH), dim3(512), 0, stream>>>(
        x, embed_w, posamp_w, posamp_b, reduce_w, reduce_b,
        dil_w, dil_b, one_w, one_b,
        aw1, aw2, pw1, pw2, aw3, l2c);

    k_tail<<<dim3(8, NBATCH), dim3(512), 0, stream>>>(
        l2c, dil_w, dil_b, one_w, one_b,
        aw1, ab1, aw2, ab2, aw3, ab3,
        pw1, pb1, pw2, pb2, pw3, pb3, (float*)d_out);
}